// Round 9
// baseline (329.807 us; speedup 1.0000x reference)
//
#include <hip/hip_runtime.h>
#include <math.h>

// ---------------------------------------------------------------------------
// 3-layer GCN, CSR-gather formulation.
// Round 22 (= R21 + one-line fix): R21 crashed because k_csr took the
// bucket's padded total from sm[1023], but the 512-step Hillis-Steele scan
// only sums a 512-wide window -> sm[1023] = 0 -> pad prefill skipped ->
// garbage byte offsets in esrcb -> OOB gathers -> device fault.
// Fix: ptot = sm[RNODES-1] (full 0..511 sum).  Rest identical to R21:
//   - padded CSR (esrcb): per-node edge list padded to x16, pads -> zero row
//   - rpd[node] = {padded start, niter} single 8B load
//   - esrcb stores byte offsets (s<<7); quad reads 4 edges via one uint4
//   - no gates/clamps/tail in gather loop (~38% VALU cut at VALUBusy~80%)
// N=100000, E=1200000, F: 128 -> 64 -> 64 -> 40
// ---------------------------------------------------------------------------

static inline int cdiv(long a, int b) { return (int)((a + b - 1) / b); }

// ---- bf16 helpers (RNE) ----
__device__ __forceinline__ unsigned short f2bf(float f) {
    unsigned u = __float_as_uint(f);
    u += 0x7fffu + ((u >> 16) & 1u);
    return (unsigned short)(u >> 16);
}
__device__ __forceinline__ float bf2f(unsigned short b) {
    return __uint_as_float(((unsigned)b) << 16);
}

// ---- radix-bucket CSR build ----
#define RSH 9
#define RNODES 512            // 1 << RSH nodes per bucket
#define GB 1024               // blocks in bucket-hist / bucket-scatter passes
#define NBMAX 256             // max buckets (N <= 131072)
#define SMASK 0x1FFFF         // 17-bit src mask (N <= 131072)
#define PSLACK (RNODES * 16)  // per-bucket padding slack (8192 entries)

// K1: per-block bucket histogram (LDS atomics only).
__global__ __launch_bounds__(256)
void k_bhist(const int* __restrict__ dst, int* __restrict__ bh,
             int E, int NB, int EPB) {
    __shared__ int bcnt[NBMAX];
    const int tid = threadIdx.x, blk = blockIdx.x;
    for (int i = tid; i < NB; i += 256) bcnt[i] = 0;
    __syncthreads();
    const int e1 = min(E, (blk + 1) * EPB);
    for (int e = blk * EPB + tid; e < e1; e += 256)
        atomicAdd(&bcnt[dst[e] >> RSH], 1);
    __syncthreads();
    for (int i = tid; i < NB; i += 256) bh[i * GB + blk] = bcnt[i];
}

// K2: scatter edges into bucket-grouped ebuf (LDS cursors, no global atomics).
// Packed entry: (dst & 511) << 17 | src.
__global__ __launch_bounds__(256)
void k_bscatter(const int* __restrict__ src, const int* __restrict__ dst,
                const int* __restrict__ eoff, int* __restrict__ ebuf,
                int E, int NB, int EPB) {
    __shared__ int cur[NBMAX];
    const int tid = threadIdx.x, blk = blockIdx.x;
    for (int i = tid; i < NB; i += 256) cur[i] = eoff[i * GB + blk];
    __syncthreads();
    const int e1 = min(E, (blk + 1) * EPB);
    for (int e = blk * EPB + tid; e < e1; e += 256) {
        int d = dst[e];
        int s = src[e];
        int pos = atomicAdd(&cur[d >> RSH], 1);
        ebuf[pos] = ((d & (RNODES - 1)) << 17) | s;
    }
}

// K3: per-bucket CSR finalize -> PADDED esrcb (byte offsets) + rpd + dis.
// Per-node padded length = ceil(deg/16)*16; pads point at zero row N.
__global__ __launch_bounds__(1024)
void k_csr(const int* __restrict__ ebuf, const int* __restrict__ eoff,
           uint2* __restrict__ rpd, float* __restrict__ dis,
           unsigned int* __restrict__ esrcb, int N, int E, int NB) {
    __shared__ int cnt[RNODES];
    __shared__ int cur[RNODES];
    __shared__ int sm[1024];
    const int tid = threadIdx.x, b = blockIdx.x;
    const int node0 = b << RSH;
    const int bb = eoff[b * GB];
    const int be = (b + 1 == NB) ? E : eoff[(b + 1) * GB];
    const int pbase = ((bb + 15) & ~15) + b * PSLACK;   // 16-aligned

    if (tid < RNODES) cnt[tid] = 0;
    __syncthreads();
    for (int e = bb + tid; e < be; e += 1024)
        atomicAdd(&cnt[ebuf[e] >> 17], 1);
    __syncthreads();

    // exclusive scan of PADDED counts (window covers 0..511 for tid < 512)
    int v  = (tid < RNODES) ? cnt[tid] : 0;
    int pv = (v + 15) & ~15;
    sm[tid] = pv;
    __syncthreads();
    for (int off = 1; off < RNODES; off <<= 1) {
        int t = (tid >= off) ? sm[tid - off] : 0;
        __syncthreads();
        sm[tid] += t;
        __syncthreads();
    }
    if (tid < RNODES) {
        int excl = sm[tid] - pv;
        cur[tid] = pbase + excl;               // absolute padded cursor
        int node = node0 + tid;
        if (node < N) {
            rpd[node] = make_uint2((unsigned)(pbase + excl), (unsigned)((v + 15) >> 4));
            dis[node] = rsqrtf(1.0f + (float)v);   // +1 self-loop
        }
    }
    __syncthreads();
    // R22 FIX: total padded entries = sm[511] (sm[1023]'s 512-wide window
    // sums only zeros -> R21 skipped the prefill -> garbage offsets -> fault)
    const int ptot = sm[RNODES - 1];

    // pre-fill padded region with zero-row byte offset
    const unsigned ZOFF = (unsigned)N << 7;
    for (int k = tid; k < ptot; k += 1024) esrcb[pbase + k] = ZOFF;
    __syncthreads();

    // rank-scatter real edges (byte offsets s << 7)
    for (int e = bb + tid; e < be; e += 1024) {
        int ev = ebuf[e];
        int slot = atomicAdd(&cur[ev >> 17], 1);
        esrcb[slot] = (unsigned)(ev & SMASK) << 7;
    }
}

// ---- 3-step exclusive scan (for the [bucket][block] matrix) ----
#define SCAN_B 1024
// block 0 additionally zeroes the 128 B zero-row (row N of buf0).
__global__ void k_scan1(const int* __restrict__ cnt, int* __restrict__ rp,
                        int* __restrict__ bsum, int n, unsigned* __restrict__ zrow) {
    __shared__ int sm[SCAN_B];
    const int tid = threadIdx.x;
    const int gid = blockIdx.x * SCAN_B + tid;
    if (blockIdx.x == 0 && tid >= 992) zrow[tid - 992] = 0;   // 32 x 4 B = 128 B
    int v = (gid < n) ? cnt[gid] : 0;
    sm[tid] = v;
    __syncthreads();
    for (int off = 1; off < SCAN_B; off <<= 1) {
        int t = (tid >= off) ? sm[tid - off] : 0;
        __syncthreads();
        sm[tid] += t;
        __syncthreads();
    }
    if (gid < n) rp[gid] = sm[tid] - v;           // exclusive
    if (tid == SCAN_B - 1) bsum[blockIdx.x] = sm[tid];
}

__global__ void k_scan2(int* __restrict__ bsum, int nb) {
    __shared__ int sm[SCAN_B];
    const int tid = threadIdx.x;
    int v = (tid < nb) ? bsum[tid] : 0;
    sm[tid] = v;
    __syncthreads();
    for (int off = 1; off < SCAN_B; off <<= 1) {
        int t = (tid >= off) ? sm[tid - off] : 0;
        __syncthreads();
        sm[tid] += t;
        __syncthreads();
    }
    if (tid < nb) bsum[tid] = sm[tid] - v;        // exclusive
}

__global__ void k_scan3(int* __restrict__ rp, const int* __restrict__ bsum, int n, int E) {
    const int gid = blockIdx.x * SCAN_B + threadIdx.x;
    if (gid < n) rp[gid] += bsum[gid / SCAN_B];
    if (gid == n) rp[n] = E;
}

__device__ __forceinline__ void fma4(float a, const float4& w, float4& acc) {
    acc.x = fmaf(a, w.x, acc.x);
    acc.y = fmaf(a, w.y, acc.y);
    acc.z = fmaf(a, w.z, acc.z);
    acc.w = fmaf(a, w.w, acc.w);
}

// LDS-tiled GEMM with fused dis-scale: Hs[N,64] = (X[N,K] @ W[K,64]) * dis[row].
// BF16IN: X rows are bf16 (stage converts to f32 in LDS; math unchanged).
template<int K, bool BF16IN, int MINW>
__global__ __launch_bounds__(256, MINW)
void k_gemm_lds(const void* __restrict__ Xv, const float* __restrict__ W,
                const float* __restrict__ dis, void* __restrict__ Hout, int N) {
    constexpr int KP = K + 4;                 // padded X row stride (floats)
    __shared__ float xs[64 * KP];
    __shared__ float wsh[K * 64];
    const int tid = threadIdx.x;
    const int tx = tid & 15;                  // col group (4 cols)
    const int ty = tid >> 4;                  // row group (4 rows)
    const int row0 = blockIdx.x * 64;

    {
        const float4* Wg = (const float4*)W;
        float4* Wl = (float4*)wsh;
#pragma unroll
        for (int i = 0; i < K * 16 / 256; ++i)
            Wl[i * 256 + tid] = Wg[i * 256 + tid];
    }
    {
        constexpr int F4 = K / 4;             // 4-elem groups per row
        for (int i = tid; i < 64 * F4; i += 256) {
            int r = i / F4, c = i - r * F4;
            int gr = min(row0 + r, N - 1);
            float4 v;
            if (BF16IN) {
                ushort4 u = *(const ushort4*)((const unsigned short*)Xv + (size_t)gr * K + c * 4);
                v.x = bf2f(u.x); v.y = bf2f(u.y); v.z = bf2f(u.z); v.w = bf2f(u.w);
            } else {
                v = *(const float4*)((const float*)Xv + (size_t)gr * K + c * 4);
            }
            *(float4*)(xs + r * KP + c * 4) = v;
        }
    }
    __syncthreads();

    float4 acc0 = {0.f, 0.f, 0.f, 0.f};
    float4 acc1 = {0.f, 0.f, 0.f, 0.f};
    float4 acc2 = {0.f, 0.f, 0.f, 0.f};
    float4 acc3 = {0.f, 0.f, 0.f, 0.f};

    const float* xr0 = xs + (ty * 4 + 0) * KP;
    const float* xr1 = xs + (ty * 4 + 1) * KP;
    const float* xr2 = xs + (ty * 4 + 2) * KP;
    const float* xr3 = xs + (ty * 4 + 3) * KP;

#pragma unroll 2
    for (int k = 0; k < K; k += 4) {
        float4 w0 = *(const float4*)(wsh + (k + 0) * 64 + tx * 4);
        float4 w1 = *(const float4*)(wsh + (k + 1) * 64 + tx * 4);
        float4 w2 = *(const float4*)(wsh + (k + 2) * 64 + tx * 4);
        float4 w3 = *(const float4*)(wsh + (k + 3) * 64 + tx * 4);
        float4 xa = *(const float4*)(xr0 + k);
        float4 xb = *(const float4*)(xr1 + k);
        float4 xc = *(const float4*)(xr2 + k);
        float4 xd = *(const float4*)(xr3 + k);

        fma4(xa.x, w0, acc0); fma4(xa.y, w1, acc0); fma4(xa.z, w2, acc0); fma4(xa.w, w3, acc0);
        fma4(xb.x, w0, acc1); fma4(xb.y, w1, acc1); fma4(xb.z, w2, acc1); fma4(xb.w, w3, acc1);
        fma4(xc.x, w0, acc2); fma4(xc.y, w1, acc2); fma4(xc.z, w2, acc2); fma4(xc.w, w3, acc2);
        fma4(xd.x, w0, acc3); fma4(xd.y, w1, acc3); fma4(xd.z, w2, acc3); fma4(xd.w, w3, acc3);
    }

    const int r = row0 + ty * 4;
#pragma unroll
    for (int i = 0; i < 4; ++i) {
        if (r + i >= N) break;
        float4 a = (i == 0) ? acc0 : (i == 1) ? acc1 : (i == 2) ? acc2 : acc3;
        float d = dis[r + i];
        a.x *= d; a.y *= d; a.z *= d; a.w *= d;
        ushort4 o;
        o.x = f2bf(a.x); o.y = f2bf(a.y); o.z = f2bf(a.z); o.w = f2bf(a.w);
        *(ushort4*)((unsigned short*)Hout + (size_t)(r + i) * 64 + tx * 4) = o;
    }
}

// Wave-per-node segmented row-sum over padded CSR (byte-offset esrcb).
// Quad q reads 4 CONSECUTIVE edges via one uint4; no gates/clamps/tail.
// MODE 0: A = relu(t + bias)           -> bf16  (a1, gemm64 input)
// MODE 1: A = relu(t + bias) * dis[d]  -> bf16  (a2s, zgemm input)
template<int MODE>
__global__ __launch_bounds__(256, 8)
void k_agg(const unsigned short* __restrict__ Hs, const float* __restrict__ dis,
           const uint2* __restrict__ rpd, const unsigned int* __restrict__ esrcb,
           const float* __restrict__ bias, void* __restrict__ A, int N) {
    const int wave = threadIdx.x >> 6;
    const int lane = threadIdx.x & 63;
    const int node = blockIdx.x * (blockDim.x >> 6) + wave;
    if (node >= N) return;
    const int q    = lane >> 4;        // quad 0..3 -> 4 consecutive edges each
    const unsigned foff = (lane & 15) * 8;   // byte offset within 128 B row

    const uint2 pd = rpd[node];
    const char* base = (const char*)Hs;
    float4 acc = {0.f, 0.f, 0.f, 0.f};
    unsigned e = pd.x + q * 4;
    for (unsigned it = 0; it < pd.y; ++it, e += 16) {
        uint4 ov = *(const uint4*)(esrcb + e);
        ushort4 h0 = *(const ushort4*)(base + (ov.x + foff));
        ushort4 h1 = *(const ushort4*)(base + (ov.y + foff));
        ushort4 h2 = *(const ushort4*)(base + (ov.z + foff));
        ushort4 h3 = *(const ushort4*)(base + (ov.w + foff));
        acc.x += (bf2f(h0.x) + bf2f(h1.x)) + (bf2f(h2.x) + bf2f(h3.x));
        acc.y += (bf2f(h0.y) + bf2f(h1.y)) + (bf2f(h2.y) + bf2f(h3.y));
        acc.z += (bf2f(h0.z) + bf2f(h1.z)) + (bf2f(h2.z) + bf2f(h3.z));
        acc.w += (bf2f(h0.w) + bf2f(h1.w)) + (bf2f(h2.w) + bf2f(h3.w));
    }
    // cross-quad reduce (after: lanes 0..15 hold the full row sum)
    acc.x += __shfl_xor(acc.x, 16, 64);
    acc.y += __shfl_xor(acc.y, 16, 64);
    acc.z += __shfl_xor(acc.z, 16, 64);
    acc.w += __shfl_xor(acc.w, 16, 64);
    acc.x += __shfl_xor(acc.x, 32, 64);
    acc.y += __shfl_xor(acc.y, 32, 64);
    acc.z += __shfl_xor(acc.z, 32, 64);
    acc.w += __shfl_xor(acc.w, 32, 64);

    if (lane < 16) {
        const float dd = dis[node];
        ushort4 sh = *(const ushort4*)(Hs + (size_t)node * 64 + lane * 4);
        float4 v;
        v.x = (acc.x + bf2f(sh.x)) * dd;
        v.y = (acc.y + bf2f(sh.y)) * dd;
        v.z = (acc.z + bf2f(sh.z)) * dd;
        v.w = (acc.w + bf2f(sh.w)) * dd;
        float4 bv = ((const float4*)bias)[lane];
        v.x = fmaxf(v.x + bv.x, 0.f);
        v.y = fmaxf(v.y + bv.y, 0.f);
        v.z = fmaxf(v.z + bv.z, 0.f);
        v.w = fmaxf(v.w + bv.w, 0.f);
        if (MODE == 1) {
            v.x *= dd; v.y *= dd; v.z *= dd; v.w *= dd;
        }
        ushort4 o;
        o.x = f2bf(v.x); o.y = f2bf(v.y); o.z = f2bf(v.z); o.w = f2bf(v.w);
        *(ushort4*)((unsigned short*)A + (size_t)node * 64 + lane * 4) = o;
    }
}

// z64[n, 0..39] = bf16(a2s[n,:64] @ W3), row stride 64 (128 B, pad ignored).
__global__ __launch_bounds__(256, 4)
void k_zgemm(const unsigned short* __restrict__ A2s, const float* __restrict__ W,
             unsigned short* __restrict__ Z, int N, int npw) {
    const int wid  = blockIdx.x * (blockDim.x >> 6) + (threadIdx.x >> 6);
    const int lane = threadIdx.x & 63;
    const int cl   = (lane < 40) ? lane : 0;

    float w[64];
#pragma unroll
    for (int k = 0; k < 64; ++k) w[k] = W[k * 40 + cl];

    const int n0 = wid * npw;
    const int n1 = min(n0 + npw, N);
    for (int node = n0; node < n1; ++node) {
        const int un = __builtin_amdgcn_readfirstlane(node);
        const uint4* xr = (const uint4*)(A2s + (size_t)un * 64);
        float acc = 0.0f;
#pragma unroll
        for (int j = 0; j < 8; ++j) {
            uint4 u = xr[j];
            acc = fmaf(__uint_as_float(u.x << 16),          w[8 * j + 0], acc);
            acc = fmaf(__uint_as_float(u.x & 0xffff0000u),  w[8 * j + 1], acc);
            acc = fmaf(__uint_as_float(u.y << 16),          w[8 * j + 2], acc);
            acc = fmaf(__uint_as_float(u.y & 0xffff0000u),  w[8 * j + 3], acc);
            acc = fmaf(__uint_as_float(u.z << 16),          w[8 * j + 4], acc);
            acc = fmaf(__uint_as_float(u.z & 0xffff0000u),  w[8 * j + 5], acc);
            acc = fmaf(__uint_as_float(u.w << 16),          w[8 * j + 6], acc);
            acc = fmaf(__uint_as_float(u.w & 0xffff0000u),  w[8 * j + 7], acc);
        }
        if (lane < 40) Z[(size_t)node * 64 + lane] = f2bf(acc);
    }
}

// Layer-3 gather + log_softmax over z64 (128 B rows, 40 valid features).
// Same padded gather; wave-local shfl-only lsm epilogue.
__global__ __launch_bounds__(256, 8)
void k_aggz(const unsigned short* __restrict__ Z, const float* __restrict__ dis,
            const uint2* __restrict__ rpd, const unsigned int* __restrict__ esrcb,
            const float* __restrict__ b3, float* __restrict__ out, int N) {
    const int wave = threadIdx.x >> 6;
    const int lane = threadIdx.x & 63;
    const int node = blockIdx.x * (blockDim.x >> 6) + wave;
    if (node >= N) return;
    const int q    = lane >> 4;
    const int f4   = lane & 15;
    const unsigned foff = f4 * 8;

    const uint2 pd = rpd[node];
    const char* base = (const char*)Z;
    float4 acc = {0.f, 0.f, 0.f, 0.f};
    unsigned e = pd.x + q * 4;
    for (unsigned it = 0; it < pd.y; ++it, e += 16) {
        uint4 ov = *(const uint4*)(esrcb + e);
        ushort4 h0 = *(const ushort4*)(base + (ov.x + foff));
        ushort4 h1 = *(const ushort4*)(base + (ov.y + foff));
        ushort4 h2 = *(const ushort4*)(base + (ov.z + foff));
        ushort4 h3 = *(const ushort4*)(base + (ov.w + foff));
        acc.x += (bf2f(h0.x) + bf2f(h1.x)) + (bf2f(h2.x) + bf2f(h3.x));
        acc.y += (bf2f(h0.y) + bf2f(h1.y)) + (bf2f(h2.y) + bf2f(h3.y));
        acc.z += (bf2f(h0.z) + bf2f(h1.z)) + (bf2f(h2.z) + bf2f(h3.z));
        acc.w += (bf2f(h0.w) + bf2f(h1.w)) + (bf2f(h2.w) + bf2f(h3.w));
    }
    // cross-quad reduce: all lanes end with the full 4-feature sums for f4
    acc.x += __shfl_xor(acc.x, 16, 64);
    acc.y += __shfl_xor(acc.y, 16, 64);
    acc.z += __shfl_xor(acc.z, 16, 64);
    acc.w += __shfl_xor(acc.w, 16, 64);
    acc.x += __shfl_xor(acc.x, 32, 64);
    acc.y += __shfl_xor(acc.y, 32, 64);
    acc.z += __shfl_xor(acc.z, 32, 64);
    acc.w += __shfl_xor(acc.w, 32, 64);

    // wave-local log-softmax over features 0..39 (f4 < 10)
    const float dd = dis[node];
    ushort4 sh = *(const ushort4*)(Z + (size_t)node * 64 + f4 * 4);
    float4 bv = {0.f, 0.f, 0.f, 0.f};
    if (f4 < 10) bv = ((const float4*)b3)[f4];
    float4 v;
    v.x = (acc.x + bf2f(sh.x)) * dd + bv.x;
    v.y = (acc.y + bf2f(sh.y)) * dd + bv.y;
    v.z = (acc.z + bf2f(sh.z)) * dd + bv.z;
    v.w = (acc.w + bf2f(sh.w)) * dd + bv.w;

    float m = (f4 < 10) ? fmaxf(fmaxf(v.x, v.y), fmaxf(v.z, v.w)) : -INFINITY;
#pragma unroll
    for (int o = 1; o < 16; o <<= 1) m = fmaxf(m, __shfl_xor(m, o, 64));
    float es = (f4 < 10)
        ? expf(v.x - m) + expf(v.y - m) + expf(v.z - m) + expf(v.w - m) : 0.f;
#pragma unroll
    for (int o = 1; o < 16; o <<= 1) es += __shfl_xor(es, o, 64);

    if (lane < 10) {                   // q==0 && f4<10
        float ls = logf(es);
        float4 o4;
        o4.x = v.x - m - ls;
        o4.y = v.y - m - ls;
        o4.z = v.z - m - ls;
        o4.w = v.w - m - ls;
        *(float4*)(out + (size_t)node * 40 + lane * 4) = o4;
    }
}

extern "C" void kernel_launch(void* const* d_in, const int* in_sizes, int n_in,
                              void* d_out, int out_size, void* d_ws, size_t ws_size,
                              hipStream_t stream) {
    const float* x  = (const float*)d_in[0];
    const int*   ei = (const int*)d_in[1];
    const float* W1 = (const float*)d_in[2];
    const float* b1 = (const float*)d_in[3];
    const float* W2 = (const float*)d_in[4];
    const float* b2 = (const float*)d_in[5];
    const float* W3 = (const float*)d_in[6];
    const float* b3 = (const float*)d_in[7];
    float* out = (float*)d_out;

    const int N = in_sizes[0] / 128;
    const int E = in_sizes[1] / 2;
    const int* src = ei;
    const int* dst = ei + E;

    const int NB   = cdiv(N, RNODES);        // buckets (196 @ N=100000)
    const int EPB  = cdiv(E, GB);            // edges per hist/scatter block
    const int nscan = NB * GB;               // scan length (200704)
    const size_t esz = (size_t)E + (size_t)(NB + 2) * PSLACK + 64; // padded esrcb len

    // ---- workspace layout ----
    // buf0: Hs1 bf16 -> Hs2 bf16 -> z64 bf16 (+ zero row N)
    // buf1: a1 bf16 -> a2s bf16
    char* ws = (char*)d_ws;
    char* buf0  = ws;                         ws += (size_t)(N + 1) * 128;          // 12.8 MB (+zero row)
    char* buf1  = ws;                         ws += (size_t)N * 128;                // 12.8 MB
    unsigned* esrcb = (unsigned*)ws;          ws += esz * sizeof(int);              // ~11.3 MB
    uint2* rpd  = (uint2*)ws;                 ws += (size_t)N * sizeof(uint2);      // 800 KB
    int*   bsum  = (int*)ws;                  ws += (size_t)SCAN_B * sizeof(int);
    float* dis   = (float*)ws;                ws += (size_t)N * sizeof(float);
    int*   bh    = (int*)ws;                  ws += (size_t)nscan * sizeof(int);    // 803 KB
    int*   eoff  = (int*)ws;                  ws += (size_t)(nscan + 1) * sizeof(int);
    int*   ebuf  = (int*)(ws);                ws += (size_t)E * sizeof(int);        // 4.8 MB

    const int B = 256;
    const int nbs = cdiv(nscan, SCAN_B);

    // ---- CSR build: two-level counting sort, zero global atomics ----
    k_bhist<<<GB, B, 0, stream>>>(dst, bh, E, NB, EPB);
    k_scan1<<<nbs, SCAN_B, 0, stream>>>(bh, eoff, bsum, nscan,
                                        (unsigned*)(buf0 + (size_t)N * 128));
    k_scan2<<<1, SCAN_B, 0, stream>>>(bsum, nbs);
    k_scan3<<<cdiv(nscan + 1, SCAN_B), SCAN_B, 0, stream>>>(eoff, bsum, nscan, E);
    k_bscatter<<<GB, B, 0, stream>>>(src, dst, eoff, ebuf, E, NB, EPB);
    k_csr<<<NB, 1024, 0, stream>>>(ebuf, eoff, rpd, dis, esrcb, N, E, NB);

    // ---- layer 1: Hs1 = bf16((x@W1)*dis); a1 = bf16(relu(dis*sum + b1)) ----
    k_gemm_lds<128, false, 2><<<cdiv(N, 64), B, 0, stream>>>(x, W1, dis, buf0, N);
    k_agg<0><<<cdiv(N, 4), B, 0, stream>>>((const unsigned short*)buf0, dis, rpd, esrcb,
                                           b1, buf1, N);

    // ---- layer 2: Hs2 = bf16((a1@W2)*dis); a2s = bf16(relu(dis*sum+b2)*dis) ----
    k_gemm_lds<64, true, 4><<<cdiv(N, 64), B, 0, stream>>>(buf1, W2, dis, buf0, N);
    k_agg<1><<<cdiv(N, 4), B, 0, stream>>>((const unsigned short*)buf0, dis, rpd, esrcb,
                                           b2, buf1, N);

    // ---- layer 3: z64 = a2s @ W3 (stride-64 rows); out = lsm gather ----
    const int NW = 8192;                      // 2048 blocks x 4 waves
    const int npw = cdiv(N, NW);
    k_zgemm<<<NW / 4, B, 0, stream>>>((const unsigned short*)buf1, W3,
                                      (unsigned short*)buf0, N, npw);
    k_aggz<<<cdiv(N, 4), B, 0, stream>>>((const unsigned short*)buf0, dis, rpd, esrcb,
                                         b3, out, N);
}

// Round 10
// 314.930 us; speedup vs baseline: 1.0472x; 1.0472x over previous
//
#include <hip/hip_runtime.h>
#include <math.h>

// ---------------------------------------------------------------------------
// 3-layer GCN, CSR-gather formulation.
// Round 23: fp8 (OCP e4m3) Hs gather tables.
//   R22 verdict: gathers pinned at FETCH/dur ~1.5 TB/s across ALL structures
//   (VALU cut -> VALUBusy 80->67% but time flat) => random-line FILL floor.
//   Only lever left: fewer bytes. 64-feat fp8 row = 64 B = ONE cache line
//   (bf16 = 2). Hs1/Hs2 stored fp8 via gfx950 HW cvt (v_cvt_pk_*_fp8);
//   z-table stays bf16 (logit-direct error, no downstream averaging).
//   esrcb stores s<<6 (fp8 row bytes); aggz rescales by <<1 for 128 B z rows.
//   Predict: agg 44.5->~30 each (FETCH 69->~46 MB), absmax ~0.03-0.07
//   (R4 measured 0.0625 passes).
// N=100000, E=1200000, F: 128 -> 64 -> 64 -> 40
// ---------------------------------------------------------------------------

static inline int cdiv(long a, int b) { return (int)((a + b - 1) / b); }

// ---- bf16 helpers (RNE) ----
__device__ __forceinline__ unsigned short f2bf(float f) {
    unsigned u = __float_as_uint(f);
    u += 0x7fffu + ((u >> 16) & 1u);
    return (unsigned short)(u >> 16);
}
__device__ __forceinline__ float bf2f(unsigned short b) {
    return __uint_as_float(((unsigned)b) << 16);
}

// ---- fp8 e4m3 (OCP) helpers via gfx950 HW cvt ----
typedef float floatx2 __attribute__((ext_vector_type(2)));
__device__ __forceinline__ float4 fp8x4_f(unsigned u) {
    floatx2 lo = __builtin_amdgcn_cvt_pk_f32_fp8(u, false);  // bytes 0,1
    floatx2 hi = __builtin_amdgcn_cvt_pk_f32_fp8(u, true);   // bytes 2,3
    float4 r; r.x = lo[0]; r.y = lo[1]; r.z = hi[0]; r.w = hi[1];
    return r;
}
__device__ __forceinline__ unsigned f_fp8x4(float4 v) {
    unsigned r = 0;
    r = __builtin_amdgcn_cvt_pk_fp8_f32(v.x, v.y, r, false); // bytes 0,1
    r = __builtin_amdgcn_cvt_pk_fp8_f32(v.z, v.w, r, true);  // bytes 2,3
    return r;
}

// ---- radix-bucket CSR build ----
#define RSH 9
#define RNODES 512            // 1 << RSH nodes per bucket
#define GB 1024               // blocks in bucket-hist / bucket-scatter passes
#define NBMAX 256             // max buckets (N <= 131072)
#define SMASK 0x1FFFF         // 17-bit src mask (N <= 131072)
#define PSLACK (RNODES * 16)  // per-bucket padding slack (8192 entries)

// K1: per-block bucket histogram (LDS atomics only).
__global__ __launch_bounds__(256)
void k_bhist(const int* __restrict__ dst, int* __restrict__ bh,
             int E, int NB, int EPB) {
    __shared__ int bcnt[NBMAX];
    const int tid = threadIdx.x, blk = blockIdx.x;
    for (int i = tid; i < NB; i += 256) bcnt[i] = 0;
    __syncthreads();
    const int e1 = min(E, (blk + 1) * EPB);
    for (int e = blk * EPB + tid; e < e1; e += 256)
        atomicAdd(&bcnt[dst[e] >> RSH], 1);
    __syncthreads();
    for (int i = tid; i < NB; i += 256) bh[i * GB + blk] = bcnt[i];
}

// K2: scatter edges into bucket-grouped ebuf (LDS cursors, no global atomics).
// Packed entry: (dst & 511) << 17 | src.
__global__ __launch_bounds__(256)
void k_bscatter(const int* __restrict__ src, const int* __restrict__ dst,
                const int* __restrict__ eoff, int* __restrict__ ebuf,
                int E, int NB, int EPB) {
    __shared__ int cur[NBMAX];
    const int tid = threadIdx.x, blk = blockIdx.x;
    for (int i = tid; i < NB; i += 256) cur[i] = eoff[i * GB + blk];
    __syncthreads();
    const int e1 = min(E, (blk + 1) * EPB);
    for (int e = blk * EPB + tid; e < e1; e += 256) {
        int d = dst[e];
        int s = src[e];
        int pos = atomicAdd(&cur[d >> RSH], 1);
        ebuf[pos] = ((d & (RNODES - 1)) << 17) | s;
    }
}

// K3: per-bucket CSR finalize -> PADDED esrcb (fp8-row byte offsets s<<6)
// + rpd + dis.  Per-node padded length = ceil(deg/16)*16; pads -> zero row N.
__global__ __launch_bounds__(1024)
void k_csr(const int* __restrict__ ebuf, const int* __restrict__ eoff,
           uint2* __restrict__ rpd, float* __restrict__ dis,
           unsigned int* __restrict__ esrcb, int N, int E, int NB) {
    __shared__ int cnt[RNODES];
    __shared__ int cur[RNODES];
    __shared__ int sm[1024];
    const int tid = threadIdx.x, b = blockIdx.x;
    const int node0 = b << RSH;
    const int bb = eoff[b * GB];
    const int be = (b + 1 == NB) ? E : eoff[(b + 1) * GB];
    const int pbase = ((bb + 15) & ~15) + b * PSLACK;   // 16-aligned

    if (tid < RNODES) cnt[tid] = 0;
    __syncthreads();
    for (int e = bb + tid; e < be; e += 1024)
        atomicAdd(&cnt[ebuf[e] >> 17], 1);
    __syncthreads();

    // exclusive scan of PADDED counts (window covers 0..511 for tid < 512)
    int v  = (tid < RNODES) ? cnt[tid] : 0;
    int pv = (v + 15) & ~15;
    sm[tid] = pv;
    __syncthreads();
    for (int off = 1; off < RNODES; off <<= 1) {
        int t = (tid >= off) ? sm[tid - off] : 0;
        __syncthreads();
        sm[tid] += t;
        __syncthreads();
    }
    if (tid < RNODES) {
        int excl = sm[tid] - pv;
        cur[tid] = pbase + excl;               // absolute padded cursor
        int node = node0 + tid;
        if (node < N) {
            rpd[node] = make_uint2((unsigned)(pbase + excl), (unsigned)((v + 15) >> 4));
            dis[node] = rsqrtf(1.0f + (float)v);   // +1 self-loop
        }
    }
    __syncthreads();
    const int ptot = sm[RNODES - 1];           // full-bucket padded total

    // pre-fill padded region with zero-row byte offset (fp8 stride: N<<6)
    const unsigned ZOFF = (unsigned)N << 6;
    for (int k = tid; k < ptot; k += 1024) esrcb[pbase + k] = ZOFF;
    __syncthreads();

    // rank-scatter real edges (fp8-row byte offsets s << 6)
    for (int e = bb + tid; e < be; e += 1024) {
        int ev = ebuf[e];
        int slot = atomicAdd(&cur[ev >> 17], 1);
        esrcb[slot] = (unsigned)(ev & SMASK) << 6;
    }
}

// ---- 3-step exclusive scan (for the [bucket][block] matrix) ----
#define SCAN_B 1024
// block 0 additionally zeroes both zero-rows: fp8 (64 B @ N*64) and
// bf16 z (128 B @ N*128) in buf0.
__global__ void k_scan1(const int* __restrict__ cnt, int* __restrict__ rp,
                        int* __restrict__ bsum, int n, char* __restrict__ zbase,
                        int N) {
    __shared__ int sm[SCAN_B];
    const int tid = threadIdx.x;
    const int gid = blockIdx.x * SCAN_B + tid;
    if (blockIdx.x == 0) {
        if (tid < 32)                 ((unsigned*)(zbase + (size_t)N * 128))[tid] = 0;
        else if (tid < 48)            ((unsigned*)(zbase + (size_t)N * 64))[tid - 32] = 0;
    }
    int v = (gid < n) ? cnt[gid] : 0;
    sm[tid] = v;
    __syncthreads();
    for (int off = 1; off < SCAN_B; off <<= 1) {
        int t = (tid >= off) ? sm[tid - off] : 0;
        __syncthreads();
        sm[tid] += t;
        __syncthreads();
    }
    if (gid < n) rp[gid] = sm[tid] - v;           // exclusive
    if (tid == SCAN_B - 1) bsum[blockIdx.x] = sm[tid];
}

__global__ void k_scan2(int* __restrict__ bsum, int nb) {
    __shared__ int sm[SCAN_B];
    const int tid = threadIdx.x;
    int v = (tid < nb) ? bsum[tid] : 0;
    sm[tid] = v;
    __syncthreads();
    for (int off = 1; off < SCAN_B; off <<= 1) {
        int t = (tid >= off) ? sm[tid - off] : 0;
        __syncthreads();
        sm[tid] += t;
        __syncthreads();
    }
    if (tid < nb) bsum[tid] = sm[tid] - v;        // exclusive
}

__global__ void k_scan3(int* __restrict__ rp, const int* __restrict__ bsum, int n, int E) {
    const int gid = blockIdx.x * SCAN_B + threadIdx.x;
    if (gid < n) rp[gid] += bsum[gid / SCAN_B];
    if (gid == n) rp[n] = E;
}

__device__ __forceinline__ void fma4(float a, const float4& w, float4& acc) {
    acc.x = fmaf(a, w.x, acc.x);
    acc.y = fmaf(a, w.y, acc.y);
    acc.z = fmaf(a, w.z, acc.z);
    acc.w = fmaf(a, w.w, acc.w);
}

// LDS-tiled GEMM with fused dis-scale: Hs[N,64] = (X[N,K] @ W[K,64]) * dis[row].
// BF16IN: X rows are bf16. Output: fp8 e4m3 rows (64 B, one line per row).
template<int K, bool BF16IN, int MINW>
__global__ __launch_bounds__(256, MINW)
void k_gemm_lds(const void* __restrict__ Xv, const float* __restrict__ W,
                const float* __restrict__ dis, void* __restrict__ Hout, int N) {
    constexpr int KP = K + 4;                 // padded X row stride (floats)
    __shared__ float xs[64 * KP];
    __shared__ float wsh[K * 64];
    const int tid = threadIdx.x;
    const int tx = tid & 15;                  // col group (4 cols)
    const int ty = tid >> 4;                  // row group (4 rows)
    const int row0 = blockIdx.x * 64;

    {
        const float4* Wg = (const float4*)W;
        float4* Wl = (float4*)wsh;
#pragma unroll
        for (int i = 0; i < K * 16 / 256; ++i)
            Wl[i * 256 + tid] = Wg[i * 256 + tid];
    }
    {
        constexpr int F4 = K / 4;             // 4-elem groups per row
        for (int i = tid; i < 64 * F4; i += 256) {
            int r = i / F4, c = i - r * F4;
            int gr = min(row0 + r, N - 1);
            float4 v;
            if (BF16IN) {
                ushort4 u = *(const ushort4*)((const unsigned short*)Xv + (size_t)gr * K + c * 4);
                v.x = bf2f(u.x); v.y = bf2f(u.y); v.z = bf2f(u.z); v.w = bf2f(u.w);
            } else {
                v = *(const float4*)((const float*)Xv + (size_t)gr * K + c * 4);
            }
            *(float4*)(xs + r * KP + c * 4) = v;
        }
    }
    __syncthreads();

    float4 acc0 = {0.f, 0.f, 0.f, 0.f};
    float4 acc1 = {0.f, 0.f, 0.f, 0.f};
    float4 acc2 = {0.f, 0.f, 0.f, 0.f};
    float4 acc3 = {0.f, 0.f, 0.f, 0.f};

    const float* xr0 = xs + (ty * 4 + 0) * KP;
    const float* xr1 = xs + (ty * 4 + 1) * KP;
    const float* xr2 = xs + (ty * 4 + 2) * KP;
    const float* xr3 = xs + (ty * 4 + 3) * KP;

#pragma unroll 2
    for (int k = 0; k < K; k += 4) {
        float4 w0 = *(const float4*)(wsh + (k + 0) * 64 + tx * 4);
        float4 w1 = *(const float4*)(wsh + (k + 1) * 64 + tx * 4);
        float4 w2 = *(const float4*)(wsh + (k + 2) * 64 + tx * 4);
        float4 w3 = *(const float4*)(wsh + (k + 3) * 64 + tx * 4);
        float4 xa = *(const float4*)(xr0 + k);
        float4 xb = *(const float4*)(xr1 + k);
        float4 xc = *(const float4*)(xr2 + k);
        float4 xd = *(const float4*)(xr3 + k);

        fma4(xa.x, w0, acc0); fma4(xa.y, w1, acc0); fma4(xa.z, w2, acc0); fma4(xa.w, w3, acc0);
        fma4(xb.x, w0, acc1); fma4(xb.y, w1, acc1); fma4(xb.z, w2, acc1); fma4(xb.w, w3, acc1);
        fma4(xc.x, w0, acc2); fma4(xc.y, w1, acc2); fma4(xc.z, w2, acc2); fma4(xc.w, w3, acc2);
        fma4(xd.x, w0, acc3); fma4(xd.y, w1, acc3); fma4(xd.z, w2, acc3); fma4(xd.w, w3, acc3);
    }

    const int r = row0 + ty * 4;
#pragma unroll
    for (int i = 0; i < 4; ++i) {
        if (r + i >= N) break;
        float4 a = (i == 0) ? acc0 : (i == 1) ? acc1 : (i == 2) ? acc2 : acc3;
        float d = dis[r + i];
        a.x *= d; a.y *= d; a.z *= d; a.w *= d;
        unsigned o = f_fp8x4(a);
        *(unsigned*)((unsigned char*)Hout + (size_t)(r + i) * 64 + tx * 4) = o;
    }
}

// Wave-per-node segmented row-sum over padded CSR, fp8 rows (64 B, 1 line).
// Quad q reads 4 consecutive edges via one uint4; lane covers 4 features (4 B).
// MODE 0: A = relu(t + bias)           -> bf16  (a1, gemm64 input)
// MODE 1: A = relu(t + bias) * dis[d]  -> bf16  (a2s, zgemm input)
template<int MODE>
__global__ __launch_bounds__(256, 8)
void k_agg(const unsigned char* __restrict__ Hs8, const float* __restrict__ dis,
           const uint2* __restrict__ rpd, const unsigned int* __restrict__ esrcb,
           const float* __restrict__ bias, void* __restrict__ A, int N) {
    const int wave = threadIdx.x >> 6;
    const int lane = threadIdx.x & 63;
    const int node = blockIdx.x * (blockDim.x >> 6) + wave;
    if (node >= N) return;
    const int q    = lane >> 4;        // quad 0..3 -> 4 consecutive edges each
    const unsigned foff = (lane & 15) * 4;   // byte offset within 64 B fp8 row

    const uint2 pd = rpd[node];
    const char* base = (const char*)Hs8;
    float4 acc = {0.f, 0.f, 0.f, 0.f};
    unsigned e = pd.x + q * 4;
    for (unsigned it = 0; it < pd.y; ++it, e += 16) {
        uint4 ov = *(const uint4*)(esrcb + e);
        unsigned u0 = *(const unsigned*)(base + (ov.x + foff));
        unsigned u1 = *(const unsigned*)(base + (ov.y + foff));
        unsigned u2 = *(const unsigned*)(base + (ov.z + foff));
        unsigned u3 = *(const unsigned*)(base + (ov.w + foff));
        float4 h0 = fp8x4_f(u0);
        float4 h1 = fp8x4_f(u1);
        float4 h2 = fp8x4_f(u2);
        float4 h3 = fp8x4_f(u3);
        acc.x += (h0.x + h1.x) + (h2.x + h3.x);
        acc.y += (h0.y + h1.y) + (h2.y + h3.y);
        acc.z += (h0.z + h1.z) + (h2.z + h3.z);
        acc.w += (h0.w + h1.w) + (h2.w + h3.w);
    }
    // cross-quad reduce (after: lanes 0..15 hold the full row sum)
    acc.x += __shfl_xor(acc.x, 16, 64);
    acc.y += __shfl_xor(acc.y, 16, 64);
    acc.z += __shfl_xor(acc.z, 16, 64);
    acc.w += __shfl_xor(acc.w, 16, 64);
    acc.x += __shfl_xor(acc.x, 32, 64);
    acc.y += __shfl_xor(acc.y, 32, 64);
    acc.z += __shfl_xor(acc.z, 32, 64);
    acc.w += __shfl_xor(acc.w, 32, 64);

    if (lane < 16) {
        const float dd = dis[node];
        unsigned shv = *(const unsigned*)(Hs8 + (size_t)node * 64 + lane * 4);
        float4 sh = fp8x4_f(shv);
        float4 v;
        v.x = (acc.x + sh.x) * dd;
        v.y = (acc.y + sh.y) * dd;
        v.z = (acc.z + sh.z) * dd;
        v.w = (acc.w + sh.w) * dd;
        float4 bv = ((const float4*)bias)[lane];
        v.x = fmaxf(v.x + bv.x, 0.f);
        v.y = fmaxf(v.y + bv.y, 0.f);
        v.z = fmaxf(v.z + bv.z, 0.f);
        v.w = fmaxf(v.w + bv.w, 0.f);
        if (MODE == 1) {
            v.x *= dd; v.y *= dd; v.z *= dd; v.w *= dd;
        }
        ushort4 o;
        o.x = f2bf(v.x); o.y = f2bf(v.y); o.z = f2bf(v.z); o.w = f2bf(v.w);
        *(ushort4*)((unsigned short*)A + (size_t)node * 64 + lane * 4) = o;
    }
}

// z64[n, 0..39] = bf16(a2s[n,:64] @ W3), row stride 64 (128 B, pad ignored).
__global__ __launch_bounds__(256, 4)
void k_zgemm(const unsigned short* __restrict__ A2s, const float* __restrict__ W,
             unsigned short* __restrict__ Z, int N, int npw) {
    const int wid  = blockIdx.x * (blockDim.x >> 6) + (threadIdx.x >> 6);
    const int lane = threadIdx.x & 63;
    const int cl   = (lane < 40) ? lane : 0;

    float w[64];
#pragma unroll
    for (int k = 0; k < 64; ++k) w[k] = W[k * 40 + cl];

    const int n0 = wid * npw;
    const int n1 = min(n0 + npw, N);
    for (int node = n0; node < n1; ++node) {
        const int un = __builtin_amdgcn_readfirstlane(node);
        const uint4* xr = (const uint4*)(A2s + (size_t)un * 64);
        float acc = 0.0f;
#pragma unroll
        for (int j = 0; j < 8; ++j) {
            uint4 u = xr[j];
            acc = fmaf(__uint_as_float(u.x << 16),          w[8 * j + 0], acc);
            acc = fmaf(__uint_as_float(u.x & 0xffff0000u),  w[8 * j + 1], acc);
            acc = fmaf(__uint_as_float(u.y << 16),          w[8 * j + 2], acc);
            acc = fmaf(__uint_as_float(u.y & 0xffff0000u),  w[8 * j + 3], acc);
            acc = fmaf(__uint_as_float(u.z << 16),          w[8 * j + 4], acc);
            acc = fmaf(__uint_as_float(u.z & 0xffff0000u),  w[8 * j + 5], acc);
            acc = fmaf(__uint_as_float(u.w << 16),          w[8 * j + 6], acc);
            acc = fmaf(__uint_as_float(u.w & 0xffff0000u),  w[8 * j + 7], acc);
        }
        if (lane < 40) Z[(size_t)node * 64 + lane] = f2bf(acc);
    }
}

// Layer-3 gather + log_softmax over bf16 z64 (128 B rows, 40 valid features).
// esrcb entries are fp8-row offsets (s<<6) -> rescale by <<1 for 128 B rows.
__global__ __launch_bounds__(256, 8)
void k_aggz(const unsigned short* __restrict__ Z, const float* __restrict__ dis,
            const uint2* __restrict__ rpd, const unsigned int* __restrict__ esrcb,
            const float* __restrict__ b3, float* __restrict__ out, int N) {
    const int wave = threadIdx.x >> 6;
    const int lane = threadIdx.x & 63;
    const int node = blockIdx.x * (blockDim.x >> 6) + wave;
    if (node >= N) return;
    const int q    = lane >> 4;
    const int f4   = lane & 15;
    const unsigned foff = f4 * 8;

    const uint2 pd = rpd[node];
    const char* base = (const char*)Z;
    float4 acc = {0.f, 0.f, 0.f, 0.f};
    unsigned e = pd.x + q * 4;
    for (unsigned it = 0; it < pd.y; ++it, e += 16) {
        uint4 ov = *(const uint4*)(esrcb + e);
        ushort4 h0 = *(const ushort4*)(base + ((ov.x << 1) + foff));
        ushort4 h1 = *(const ushort4*)(base + ((ov.y << 1) + foff));
        ushort4 h2 = *(const ushort4*)(base + ((ov.z << 1) + foff));
        ushort4 h3 = *(const ushort4*)(base + ((ov.w << 1) + foff));
        acc.x += (bf2f(h0.x) + bf2f(h1.x)) + (bf2f(h2.x) + bf2f(h3.x));
        acc.y += (bf2f(h0.y) + bf2f(h1.y)) + (bf2f(h2.y) + bf2f(h3.y));
        acc.z += (bf2f(h0.z) + bf2f(h1.z)) + (bf2f(h2.z) + bf2f(h3.z));
        acc.w += (bf2f(h0.w) + bf2f(h1.w)) + (bf2f(h2.w) + bf2f(h3.w));
    }
    // cross-quad reduce: all lanes end with the full 4-feature sums for f4
    acc.x += __shfl_xor(acc.x, 16, 64);
    acc.y += __shfl_xor(acc.y, 16, 64);
    acc.z += __shfl_xor(acc.z, 16, 64);
    acc.w += __shfl_xor(acc.w, 16, 64);
    acc.x += __shfl_xor(acc.x, 32, 64);
    acc.y += __shfl_xor(acc.y, 32, 64);
    acc.z += __shfl_xor(acc.z, 32, 64);
    acc.w += __shfl_xor(acc.w, 32, 64);

    // wave-local log-softmax over features 0..39 (f4 < 10)
    const float dd = dis[node];
    ushort4 sh = *(const ushort4*)(Z + (size_t)node * 64 + f4 * 4);
    float4 bv = {0.f, 0.f, 0.f, 0.f};
    if (f4 < 10) bv = ((const float4*)b3)[f4];
    float4 v;
    v.x = (acc.x + bf2f(sh.x)) * dd + bv.x;
    v.y = (acc.y + bf2f(sh.y)) * dd + bv.y;
    v.z = (acc.z + bf2f(sh.z)) * dd + bv.z;
    v.w = (acc.w + bf2f(sh.w)) * dd + bv.w;

    float m = (f4 < 10) ? fmaxf(fmaxf(v.x, v.y), fmaxf(v.z, v.w)) : -INFINITY;
#pragma unroll
    for (int o = 1; o < 16; o <<= 1) m = fmaxf(m, __shfl_xor(m, o, 64));
    float es = (f4 < 10)
        ? expf(v.x - m) + expf(v.y - m) + expf(v.z - m) + expf(v.w - m) : 0.f;
#pragma unroll
    for (int o = 1; o < 16; o <<= 1) es += __shfl_xor(es, o, 64);

    if (lane < 10) {                   // q==0 && f4<10
        float ls = logf(es);
        float4 o4;
        o4.x = v.x - m - ls;
        o4.y = v.y - m - ls;
        o4.z = v.z - m - ls;
        o4.w = v.w - m - ls;
        *(float4*)(out + (size_t)node * 40 + lane * 4) = o4;
    }
}

extern "C" void kernel_launch(void* const* d_in, const int* in_sizes, int n_in,
                              void* d_out, int out_size, void* d_ws, size_t ws_size,
                              hipStream_t stream) {
    const float* x  = (const float*)d_in[0];
    const int*   ei = (const int*)d_in[1];
    const float* W1 = (const float*)d_in[2];
    const float* b1 = (const float*)d_in[3];
    const float* W2 = (const float*)d_in[4];
    const float* b2 = (const float*)d_in[5];
    const float* W3 = (const float*)d_in[6];
    const float* b3 = (const float*)d_in[7];
    float* out = (float*)d_out;

    const int N = in_sizes[0] / 128;
    const int E = in_sizes[1] / 2;
    const int* src = ei;
    const int* dst = ei + E;

    const int NB   = cdiv(N, RNODES);        // buckets (196 @ N=100000)
    const int EPB  = cdiv(E, GB);            // edges per hist/scatter block
    const int nscan = NB * GB;               // scan length (200704)
    const size_t esz = (size_t)E + (size_t)(NB + 2) * PSLACK + 64; // padded esrcb len

    // ---- workspace layout ----
    // buf0: Hs1 fp8 -> Hs2 fp8 -> z64 bf16 (+ zero rows: fp8 @ N*64, z @ N*128)
    // buf1: a1 bf16 -> a2s bf16
    char* ws = (char*)d_ws;
    char* buf0  = ws;                         ws += (size_t)(N + 1) * 128;          // 12.8 MB
    char* buf1  = ws;                         ws += (size_t)N * 128;                // 12.8 MB
    unsigned* esrcb = (unsigned*)ws;          ws += esz * sizeof(int);              // ~11.3 MB
    uint2* rpd  = (uint2*)ws;                 ws += (size_t)N * sizeof(uint2);      // 800 KB
    int*   bsum  = (int*)ws;                  ws += (size_t)SCAN_B * sizeof(int);
    float* dis   = (float*)ws;                ws += (size_t)N * sizeof(float);
    int*   bh    = (int*)ws;                  ws += (size_t)nscan * sizeof(int);    // 803 KB
    int*   eoff  = (int*)ws;                  ws += (size_t)(nscan + 1) * sizeof(int);
    int*   ebuf  = (int*)(ws);                ws += (size_t)E * sizeof(int);        // 4.8 MB

    const int B = 256;
    const int nbs = cdiv(nscan, SCAN_B);

    // ---- CSR build: two-level counting sort, zero global atomics ----
    k_bhist<<<GB, B, 0, stream>>>(dst, bh, E, NB, EPB);
    k_scan1<<<nbs, SCAN_B, 0, stream>>>(bh, eoff, bsum, nscan, buf0, N);
    k_scan2<<<1, SCAN_B, 0, stream>>>(bsum, nbs);
    k_scan3<<<cdiv(nscan + 1, SCAN_B), SCAN_B, 0, stream>>>(eoff, bsum, nscan, E);
    k_bscatter<<<GB, B, 0, stream>>>(src, dst, eoff, ebuf, E, NB, EPB);
    k_csr<<<NB, 1024, 0, stream>>>(ebuf, eoff, rpd, dis, esrcb, N, E, NB);

    // ---- layer 1: Hs1 = fp8((x@W1)*dis); a1 = bf16(relu(dis*sum + b1)) ----
    k_gemm_lds<128, false, 2><<<cdiv(N, 64), B, 0, stream>>>(x, W1, dis, buf0, N);
    k_agg<0><<<cdiv(N, 4), B, 0, stream>>>((const unsigned char*)buf0, dis, rpd, esrcb,
                                           b1, buf1, N);

    // ---- layer 2: Hs2 = fp8((a1@W2)*dis); a2s = bf16(relu(dis*sum+b2)*dis) ----
    k_gemm_lds<64, true, 4><<<cdiv(N, 64), B, 0, stream>>>(buf1, W2, dis, buf0, N);
    k_agg<1><<<cdiv(N, 4), B, 0, stream>>>((const unsigned char*)buf0, dis, rpd, esrcb,
                                           b2, buf1, N);

    // ---- layer 3: z64 = a2s @ W3 (bf16, stride-64 rows); out = lsm gather ----
    const int NW = 8192;                      // 2048 blocks x 4 waves
    const int npw = cdiv(N, NW);
    k_zgemm<<<NW / 4, B, 0, stream>>>((const unsigned short*)buf1, W3,
                                      (unsigned short*)buf0, N, npw);
    k_aggz<<<cdiv(N, 4), B, 0, stream>>>((const unsigned short*)buf0, dis, rpd, esrcb,
                                         b3, out, N);
}

// Round 12
// 305.377 us; speedup vs baseline: 1.0800x; 1.0313x over previous
//
#include <hip/hip_runtime.h>
#include <math.h>

// ---------------------------------------------------------------------------
// 3-layer GCN, CSR-gather formulation.
// Round 25 (= R24 resubmit; R24 bench died with "container failed twice" —
// same infra signature as R3, no pytest/core-dump output. Kernel audited:
// bounds, alignment, esrcb region overlap, zero-row lifetime all clean;
// fp8 builtins identical to the PASSING R23 build).
//   fp8 z-table finishes the bytes lever: z stored fp8 e4m3 at 64 B stride
//   (1 line/row), pad bytes zeroed (decode 0.0). esrcb s<<6 offsets match
//   ALL tables (no rescale). Predict aggz FETCH 69->~45 MB, 46.5->~33 us,
//   absmax ~0.03 (0.0625 measured-pass in R4 gives 2x margin).
// N=100000, E=1200000, F: 128 -> 64 -> 64 -> 40
// ---------------------------------------------------------------------------

static inline int cdiv(long a, int b) { return (int)((a + b - 1) / b); }

// ---- bf16 helpers (RNE) ----
__device__ __forceinline__ unsigned short f2bf(float f) {
    unsigned u = __float_as_uint(f);
    u += 0x7fffu + ((u >> 16) & 1u);
    return (unsigned short)(u >> 16);
}
__device__ __forceinline__ float bf2f(unsigned short b) {
    return __uint_as_float(((unsigned)b) << 16);
}

// ---- fp8 e4m3 (OCP) helpers via gfx950 HW cvt ----
typedef float floatx2 __attribute__((ext_vector_type(2)));
__device__ __forceinline__ float4 fp8x4_f(unsigned u) {
    floatx2 lo = __builtin_amdgcn_cvt_pk_f32_fp8(u, false);  // bytes 0,1
    floatx2 hi = __builtin_amdgcn_cvt_pk_f32_fp8(u, true);   // bytes 2,3
    float4 r; r.x = lo[0]; r.y = lo[1]; r.z = hi[0]; r.w = hi[1];
    return r;
}
__device__ __forceinline__ unsigned f_fp8x4(float4 v) {
    unsigned r = 0;
    r = __builtin_amdgcn_cvt_pk_fp8_f32(v.x, v.y, r, false); // bytes 0,1
    r = __builtin_amdgcn_cvt_pk_fp8_f32(v.z, v.w, r, true);  // bytes 2,3
    return r;
}

// ---- radix-bucket CSR build ----
#define RSH 9
#define RNODES 512            // 1 << RSH nodes per bucket
#define GB 1024               // blocks in bucket-hist / bucket-scatter passes
#define NBMAX 256             // max buckets (N <= 131072)
#define SMASK 0x1FFFF         // 17-bit src mask (N <= 131072)
#define PSLACK (RNODES * 16)  // per-bucket padding slack (8192 entries)

// K1: per-block bucket histogram (LDS atomics only).
__global__ __launch_bounds__(256)
void k_bhist(const int* __restrict__ dst, int* __restrict__ bh,
             int E, int NB, int EPB) {
    __shared__ int bcnt[NBMAX];
    const int tid = threadIdx.x, blk = blockIdx.x;
    for (int i = tid; i < NB; i += 256) bcnt[i] = 0;
    __syncthreads();
    const int e1 = min(E, (blk + 1) * EPB);
    for (int e = blk * EPB + tid; e < e1; e += 256)
        atomicAdd(&bcnt[dst[e] >> RSH], 1);
    __syncthreads();
    for (int i = tid; i < NB; i += 256) bh[i * GB + blk] = bcnt[i];
}

// K2: scatter edges into bucket-grouped ebuf (LDS cursors, no global atomics).
// Packed entry: (dst & 511) << 17 | src.
__global__ __launch_bounds__(256)
void k_bscatter(const int* __restrict__ src, const int* __restrict__ dst,
                const int* __restrict__ eoff, int* __restrict__ ebuf,
                int E, int NB, int EPB) {
    __shared__ int cur[NBMAX];
    const int tid = threadIdx.x, blk = blockIdx.x;
    for (int i = tid; i < NB; i += 256) cur[i] = eoff[i * GB + blk];
    __syncthreads();
    const int e1 = min(E, (blk + 1) * EPB);
    for (int e = blk * EPB + tid; e < e1; e += 256) {
        int d = dst[e];
        int s = src[e];
        int pos = atomicAdd(&cur[d >> RSH], 1);
        ebuf[pos] = ((d & (RNODES - 1)) << 17) | s;
    }
}

// K3: per-bucket CSR finalize -> PADDED esrcb (64 B-row byte offsets s<<6)
// + rpd + dis.  Per-node padded length = ceil(deg/16)*16; pads -> zero row N.
__global__ __launch_bounds__(1024)
void k_csr(const int* __restrict__ ebuf, const int* __restrict__ eoff,
           uint2* __restrict__ rpd, float* __restrict__ dis,
           unsigned int* __restrict__ esrcb, int N, int E, int NB) {
    __shared__ int cnt[RNODES];
    __shared__ int cur[RNODES];
    __shared__ int sm[1024];
    const int tid = threadIdx.x, b = blockIdx.x;
    const int node0 = b << RSH;
    const int bb = eoff[b * GB];
    const int be = (b + 1 == NB) ? E : eoff[(b + 1) * GB];
    const int pbase = ((bb + 15) & ~15) + b * PSLACK;   // 16-aligned

    if (tid < RNODES) cnt[tid] = 0;
    __syncthreads();
    for (int e = bb + tid; e < be; e += 1024)
        atomicAdd(&cnt[ebuf[e] >> 17], 1);
    __syncthreads();

    // exclusive scan of PADDED counts (window covers 0..511 for tid < 512)
    int v  = (tid < RNODES) ? cnt[tid] : 0;
    int pv = (v + 15) & ~15;
    sm[tid] = pv;
    __syncthreads();
    for (int off = 1; off < RNODES; off <<= 1) {
        int t = (tid >= off) ? sm[tid - off] : 0;
        __syncthreads();
        sm[tid] += t;
        __syncthreads();
    }
    if (tid < RNODES) {
        int excl = sm[tid] - pv;
        cur[tid] = pbase + excl;               // absolute padded cursor
        int node = node0 + tid;
        if (node < N) {
            rpd[node] = make_uint2((unsigned)(pbase + excl), (unsigned)((v + 15) >> 4));
            dis[node] = rsqrtf(1.0f + (float)v);   // +1 self-loop
        }
    }
    __syncthreads();
    const int ptot = sm[RNODES - 1];           // full-bucket padded total

    // pre-fill padded region with zero-row byte offset (stride 64 B: N<<6)
    const unsigned ZOFF = (unsigned)N << 6;
    for (int k = tid; k < ptot; k += 1024) esrcb[pbase + k] = ZOFF;
    __syncthreads();

    // rank-scatter real edges (64 B-row byte offsets s << 6)
    for (int e = bb + tid; e < be; e += 1024) {
        int ev = ebuf[e];
        int slot = atomicAdd(&cur[ev >> 17], 1);
        esrcb[slot] = (unsigned)(ev & SMASK) << 6;
    }
}

// ---- 3-step exclusive scan (for the [bucket][block] matrix) ----
#define SCAN_B 1024
// block 0 additionally zeroes the 64 B zero-row (row N of buf0).
__global__ void k_scan1(const int* __restrict__ cnt, int* __restrict__ rp,
                        int* __restrict__ bsum, int n, char* __restrict__ zbase,
                        int N) {
    __shared__ int sm[SCAN_B];
    const int tid = threadIdx.x;
    const int gid = blockIdx.x * SCAN_B + tid;
    if (blockIdx.x == 0 && tid < 16)
        ((unsigned*)(zbase + (size_t)N * 64))[tid] = 0;   // 16 x 4 B = 64 B
    int v = (gid < n) ? cnt[gid] : 0;
    sm[tid] = v;
    __syncthreads();
    for (int off = 1; off < SCAN_B; off <<= 1) {
        int t = (tid >= off) ? sm[tid - off] : 0;
        __syncthreads();
        sm[tid] += t;
        __syncthreads();
    }
    if (gid < n) rp[gid] = sm[tid] - v;           // exclusive
    if (tid == SCAN_B - 1) bsum[blockIdx.x] = sm[tid];
}

__global__ void k_scan2(int* __restrict__ bsum, int nb) {
    __shared__ int sm[SCAN_B];
    const int tid = threadIdx.x;
    int v = (tid < nb) ? bsum[tid] : 0;
    sm[tid] = v;
    __syncthreads();
    for (int off = 1; off < SCAN_B; off <<= 1) {
        int t = (tid >= off) ? sm[tid - off] : 0;
        __syncthreads();
        sm[tid] += t;
        __syncthreads();
    }
    if (tid < nb) bsum[tid] = sm[tid] - v;        // exclusive
}

__global__ void k_scan3(int* __restrict__ rp, const int* __restrict__ bsum, int n, int E) {
    const int gid = blockIdx.x * SCAN_B + threadIdx.x;
    if (gid < n) rp[gid] += bsum[gid / SCAN_B];
    if (gid == n) rp[n] = E;
}

__device__ __forceinline__ void fma4(float a, const float4& w, float4& acc) {
    acc.x = fmaf(a, w.x, acc.x);
    acc.y = fmaf(a, w.y, acc.y);
    acc.z = fmaf(a, w.z, acc.z);
    acc.w = fmaf(a, w.w, acc.w);
}

// LDS-tiled GEMM with fused dis-scale: Hs[N,64] = (X[N,K] @ W[K,64]) * dis[row].
// BF16IN: X rows are bf16. Output: fp8 e4m3 rows (64 B, one line per row).
template<int K, bool BF16IN, int MINW>
__global__ __launch_bounds__(256, MINW)
void k_gemm_lds(const void* __restrict__ Xv, const float* __restrict__ W,
                const float* __restrict__ dis, void* __restrict__ Hout, int N) {
    constexpr int KP = K + 4;                 // padded X row stride (floats)
    __shared__ float xs[64 * KP];
    __shared__ float wsh[K * 64];
    const int tid = threadIdx.x;
    const int tx = tid & 15;                  // col group (4 cols)
    const int ty = tid >> 4;                  // row group (4 rows)
    const int row0 = blockIdx.x * 64;

    {
        const float4* Wg = (const float4*)W;
        float4* Wl = (float4*)wsh;
#pragma unroll
        for (int i = 0; i < K * 16 / 256; ++i)
            Wl[i * 256 + tid] = Wg[i * 256 + tid];
    }
    {
        constexpr int F4 = K / 4;             // 4-elem groups per row
        for (int i = tid; i < 64 * F4; i += 256) {
            int r = i / F4, c = i - r * F4;
            int gr = min(row0 + r, N - 1);
            float4 v;
            if (BF16IN) {
                ushort4 u = *(const ushort4*)((const unsigned short*)Xv + (size_t)gr * K + c * 4);
                v.x = bf2f(u.x); v.y = bf2f(u.y); v.z = bf2f(u.z); v.w = bf2f(u.w);
            } else {
                v = *(const float4*)((const float*)Xv + (size_t)gr * K + c * 4);
            }
            *(float4*)(xs + r * KP + c * 4) = v;
        }
    }
    __syncthreads();

    float4 acc0 = {0.f, 0.f, 0.f, 0.f};
    float4 acc1 = {0.f, 0.f, 0.f, 0.f};
    float4 acc2 = {0.f, 0.f, 0.f, 0.f};
    float4 acc3 = {0.f, 0.f, 0.f, 0.f};

    const float* xr0 = xs + (ty * 4 + 0) * KP;
    const float* xr1 = xs + (ty * 4 + 1) * KP;
    const float* xr2 = xs + (ty * 4 + 2) * KP;
    const float* xr3 = xs + (ty * 4 + 3) * KP;

#pragma unroll 2
    for (int k = 0; k < K; k += 4) {
        float4 w0 = *(const float4*)(wsh + (k + 0) * 64 + tx * 4);
        float4 w1 = *(const float4*)(wsh + (k + 1) * 64 + tx * 4);
        float4 w2 = *(const float4*)(wsh + (k + 2) * 64 + tx * 4);
        float4 w3 = *(const float4*)(wsh + (k + 3) * 64 + tx * 4);
        float4 xa = *(const float4*)(xr0 + k);
        float4 xb = *(const float4*)(xr1 + k);
        float4 xc = *(const float4*)(xr2 + k);
        float4 xd = *(const float4*)(xr3 + k);

        fma4(xa.x, w0, acc0); fma4(xa.y, w1, acc0); fma4(xa.z, w2, acc0); fma4(xa.w, w3, acc0);
        fma4(xb.x, w0, acc1); fma4(xb.y, w1, acc1); fma4(xb.z, w2, acc1); fma4(xb.w, w3, acc1);
        fma4(xc.x, w0, acc2); fma4(xc.y, w1, acc2); fma4(xc.z, w2, acc2); fma4(xc.w, w3, acc2);
        fma4(xd.x, w0, acc3); fma4(xd.y, w1, acc3); fma4(xd.z, w2, acc3); fma4(xd.w, w3, acc3);
    }

    const int r = row0 + ty * 4;
#pragma unroll
    for (int i = 0; i < 4; ++i) {
        if (r + i >= N) break;
        float4 a = (i == 0) ? acc0 : (i == 1) ? acc1 : (i == 2) ? acc2 : acc3;
        float d = dis[r + i];
        a.x *= d; a.y *= d; a.z *= d; a.w *= d;
        unsigned o = f_fp8x4(a);
        *(unsigned*)((unsigned char*)Hout + (size_t)(r + i) * 64 + tx * 4) = o;
    }
}

// Wave-per-node segmented row-sum over padded CSR, fp8 rows (64 B, 1 line).
// Quad q reads 4 consecutive edges via one uint4; lane covers 4 features (4 B).
// MODE 0: A = relu(t + bias)           -> bf16  (a1, gemm64 input)
// MODE 1: A = relu(t + bias) * dis[d]  -> bf16  (a2s, zgemm input)
template<int MODE>
__global__ __launch_bounds__(256, 8)
void k_agg(const unsigned char* __restrict__ Hs8, const float* __restrict__ dis,
           const uint2* __restrict__ rpd, const unsigned int* __restrict__ esrcb,
           const float* __restrict__ bias, void* __restrict__ A, int N) {
    const int wave = threadIdx.x >> 6;
    const int lane = threadIdx.x & 63;
    const int node = blockIdx.x * (blockDim.x >> 6) + wave;
    if (node >= N) return;
    const int q    = lane >> 4;        // quad 0..3 -> 4 consecutive edges each
    const unsigned foff = (lane & 15) * 4;   // byte offset within 64 B fp8 row

    const uint2 pd = rpd[node];
    const char* base = (const char*)Hs8;
    float4 acc = {0.f, 0.f, 0.f, 0.f};
    unsigned e = pd.x + q * 4;
    for (unsigned it = 0; it < pd.y; ++it, e += 16) {
        uint4 ov = *(const uint4*)(esrcb + e);
        unsigned u0 = *(const unsigned*)(base + (ov.x + foff));
        unsigned u1 = *(const unsigned*)(base + (ov.y + foff));
        unsigned u2 = *(const unsigned*)(base + (ov.z + foff));
        unsigned u3 = *(const unsigned*)(base + (ov.w + foff));
        float4 h0 = fp8x4_f(u0);
        float4 h1 = fp8x4_f(u1);
        float4 h2 = fp8x4_f(u2);
        float4 h3 = fp8x4_f(u3);
        acc.x += (h0.x + h1.x) + (h2.x + h3.x);
        acc.y += (h0.y + h1.y) + (h2.y + h3.y);
        acc.z += (h0.z + h1.z) + (h2.z + h3.z);
        acc.w += (h0.w + h1.w) + (h2.w + h3.w);
    }
    // cross-quad reduce (after: lanes 0..15 hold the full row sum)
    acc.x += __shfl_xor(acc.x, 16, 64);
    acc.y += __shfl_xor(acc.y, 16, 64);
    acc.z += __shfl_xor(acc.z, 16, 64);
    acc.w += __shfl_xor(acc.w, 16, 64);
    acc.x += __shfl_xor(acc.x, 32, 64);
    acc.y += __shfl_xor(acc.y, 32, 64);
    acc.z += __shfl_xor(acc.z, 32, 64);
    acc.w += __shfl_xor(acc.w, 32, 64);

    if (lane < 16) {
        const float dd = dis[node];
        unsigned shv = *(const unsigned*)(Hs8 + (size_t)node * 64 + lane * 4);
        float4 sh = fp8x4_f(shv);
        float4 v;
        v.x = (acc.x + sh.x) * dd;
        v.y = (acc.y + sh.y) * dd;
        v.z = (acc.z + sh.z) * dd;
        v.w = (acc.w + sh.w) * dd;
        float4 bv = ((const float4*)bias)[lane];
        v.x = fmaxf(v.x + bv.x, 0.f);
        v.y = fmaxf(v.y + bv.y, 0.f);
        v.z = fmaxf(v.z + bv.z, 0.f);
        v.w = fmaxf(v.w + bv.w, 0.f);
        if (MODE == 1) {
            v.x *= dd; v.y *= dd; v.z *= dd; v.w *= dd;
        }
        ushort4 o;
        o.x = f2bf(v.x); o.y = f2bf(v.y); o.z = f2bf(v.z); o.w = f2bf(v.w);
        *(ushort4*)((unsigned short*)A + (size_t)node * 64 + lane * 4) = o;
    }
}

// z8[n, 0..39] = fp8(a2s[n,:64] @ W3), row stride 64 B (1 line); bytes 40..63
// zeroed (decode to 0.0 for idle gather lanes). One byte store per lane,
// 64 contiguous bytes per node -> single-line coalesced.
__global__ __launch_bounds__(256, 4)
void k_zgemm(const unsigned short* __restrict__ A2s, const float* __restrict__ W,
             unsigned char* __restrict__ Z8, int N, int npw) {
    const int wid  = blockIdx.x * (blockDim.x >> 6) + (threadIdx.x >> 6);
    const int lane = threadIdx.x & 63;
    const int cl   = (lane < 40) ? lane : 0;

    float w[64];
#pragma unroll
    for (int k = 0; k < 64; ++k) w[k] = W[k * 40 + cl];

    const int n0 = wid * npw;
    const int n1 = min(n0 + npw, N);
    for (int node = n0; node < n1; ++node) {
        const int un = __builtin_amdgcn_readfirstlane(node);
        const uint4* xr = (const uint4*)(A2s + (size_t)un * 64);
        float acc = 0.0f;
#pragma unroll
        for (int j = 0; j < 8; ++j) {
            uint4 u = xr[j];
            acc = fmaf(__uint_as_float(u.x << 16),          w[8 * j + 0], acc);
            acc = fmaf(__uint_as_float(u.x & 0xffff0000u),  w[8 * j + 1], acc);
            acc = fmaf(__uint_as_float(u.y << 16),          w[8 * j + 2], acc);
            acc = fmaf(__uint_as_float(u.y & 0xffff0000u),  w[8 * j + 3], acc);
            acc = fmaf(__uint_as_float(u.z << 16),          w[8 * j + 4], acc);
            acc = fmaf(__uint_as_float(u.z & 0xffff0000u),  w[8 * j + 5], acc);
            acc = fmaf(__uint_as_float(u.w << 16),          w[8 * j + 6], acc);
            acc = fmaf(__uint_as_float(u.w & 0xffff0000u),  w[8 * j + 7], acc);
        }
        unsigned p = __builtin_amdgcn_cvt_pk_fp8_f32(acc, acc, 0u, false);
        unsigned char byte = (lane < 40) ? (unsigned char)(p & 0xFFu) : (unsigned char)0;
        Z8[(size_t)node * 64 + lane] = byte;
    }
}

// Layer-3 gather + log_softmax over fp8 z rows (64 B, 1 line, 40 valid).
// Padded gather (esrcb s<<6 matches stride); wave-local shfl-only lsm.
__global__ __launch_bounds__(256, 8)
void k_aggz(const unsigned char* __restrict__ Z8, const float* __restrict__ dis,
            const uint2* __restrict__ rpd, const unsigned int* __restrict__ esrcb,
            const float* __restrict__ b3, float* __restrict__ out, int N) {
    const int wave = threadIdx.x >> 6;
    const int lane = threadIdx.x & 63;
    const int node = blockIdx.x * (blockDim.x >> 6) + wave;
    if (node >= N) return;
    const int q    = lane >> 4;
    const int f4   = lane & 15;
    const unsigned foff = f4 * 4;

    const uint2 pd = rpd[node];
    const char* base = (const char*)Z8;
    float4 acc = {0.f, 0.f, 0.f, 0.f};
    unsigned e = pd.x + q * 4;
    for (unsigned it = 0; it < pd.y; ++it, e += 16) {
        uint4 ov = *(const uint4*)(esrcb + e);
        unsigned u0 = *(const unsigned*)(base + (ov.x + foff));
        unsigned u1 = *(const unsigned*)(base + (ov.y + foff));
        unsigned u2 = *(const unsigned*)(base + (ov.z + foff));
        unsigned u3 = *(const unsigned*)(base + (ov.w + foff));
        float4 h0 = fp8x4_f(u0);
        float4 h1 = fp8x4_f(u1);
        float4 h2 = fp8x4_f(u2);
        float4 h3 = fp8x4_f(u3);
        acc.x += (h0.x + h1.x) + (h2.x + h3.x);
        acc.y += (h0.y + h1.y) + (h2.y + h3.y);
        acc.z += (h0.z + h1.z) + (h2.z + h3.z);
        acc.w += (h0.w + h1.w) + (h2.w + h3.w);
    }
    // cross-quad reduce: f4 preserved by xor 16/32 (q bits only)
    acc.x += __shfl_xor(acc.x, 16, 64);
    acc.y += __shfl_xor(acc.y, 16, 64);
    acc.z += __shfl_xor(acc.z, 16, 64);
    acc.w += __shfl_xor(acc.w, 16, 64);
    acc.x += __shfl_xor(acc.x, 32, 64);
    acc.y += __shfl_xor(acc.y, 32, 64);
    acc.z += __shfl_xor(acc.z, 32, 64);
    acc.w += __shfl_xor(acc.w, 32, 64);

    // wave-local log-softmax over features 0..39 (f4 < 10)
    const float dd = dis[node];
    unsigned shv = *(const unsigned*)(Z8 + (size_t)node * 64 + f4 * 4);
    float4 sh = fp8x4_f(shv);
    float4 bv = {0.f, 0.f, 0.f, 0.f};
    if (f4 < 10) bv = ((const float4*)b3)[f4];
    float4 v;
    v.x = (acc.x + sh.x) * dd + bv.x;
    v.y = (acc.y + sh.y) * dd + bv.y;
    v.z = (acc.z + sh.z) * dd + bv.z;
    v.w = (acc.w + sh.w) * dd + bv.w;

    float m = (f4 < 10) ? fmaxf(fmaxf(v.x, v.y), fmaxf(v.z, v.w)) : -INFINITY;
#pragma unroll
    for (int o = 1; o < 16; o <<= 1) m = fmaxf(m, __shfl_xor(m, o, 64));
    float es = (f4 < 10)
        ? expf(v.x - m) + expf(v.y - m) + expf(v.z - m) + expf(v.w - m) : 0.f;
#pragma unroll
    for (int o = 1; o < 16; o <<= 1) es += __shfl_xor(es, o, 64);

    if (lane < 10) {                   // q==0 && f4<10
        float ls = logf(es);
        float4 o4;
        o4.x = v.x - m - ls;
        o4.y = v.y - m - ls;
        o4.z = v.z - m - ls;
        o4.w = v.w - m - ls;
        *(float4*)(out + (size_t)node * 40 + lane * 4) = o4;
    }
}

extern "C" void kernel_launch(void* const* d_in, const int* in_sizes, int n_in,
                              void* d_out, int out_size, void* d_ws, size_t ws_size,
                              hipStream_t stream) {
    const float* x  = (const float*)d_in[0];
    const int*   ei = (const int*)d_in[1];
    const float* W1 = (const float*)d_in[2];
    const float* b1 = (const float*)d_in[3];
    const float* W2 = (const float*)d_in[4];
    const float* b2 = (const float*)d_in[5];
    const float* W3 = (const float*)d_in[6];
    const float* b3 = (const float*)d_in[7];
    float* out = (float*)d_out;

    const int N = in_sizes[0] / 128;
    const int E = in_sizes[1] / 2;
    const int* src = ei;
    const int* dst = ei + E;

    const int NB   = cdiv(N, RNODES);        // buckets (196 @ N=100000)
    const int EPB  = cdiv(E, GB);            // edges per hist/scatter block
    const int nscan = NB * GB;               // scan length (200704)
    const size_t esz = (size_t)E + (size_t)(NB + 2) * PSLACK + 64; // padded esrcb len

    // ---- workspace layout ----
    // buf0 (64 B rows + zero row N): Hs1 fp8 -> Hs2 fp8 -> z fp8
    // buf1: a1 bf16 -> a2s bf16 (128 B rows)
    char* ws = (char*)d_ws;
    char* buf0  = ws;                         ws += (size_t)(N + 1) * 64;           // 6.4 MB
    char* buf1  = ws;                         ws += (size_t)N * 128;                // 12.8 MB
    unsigned* esrcb = (unsigned*)ws;          ws += esz * sizeof(int);              // ~11.3 MB
    uint2* rpd  = (uint2*)ws;                 ws += (size_t)N * sizeof(uint2);      // 800 KB
    int*   bsum  = (int*)ws;                  ws += (size_t)SCAN_B * sizeof(int);
    float* dis   = (float*)ws;                ws += (size_t)N * sizeof(float);
    int*   bh    = (int*)ws;                  ws += (size_t)nscan * sizeof(int);    // 803 KB
    int*   eoff  = (int*)ws;                  ws += (size_t)(nscan + 1) * sizeof(int);
    int*   ebuf  = (int*)(ws);                ws += (size_t)E * sizeof(int);        // 4.8 MB

    const int B = 256;
    const int nbs = cdiv(nscan, SCAN_B);

    // ---- CSR build: two-level counting sort, zero global atomics ----
    k_bhist<<<GB, B, 0, stream>>>(dst, bh, E, NB, EPB);
    k_scan1<<<nbs, SCAN_B, 0, stream>>>(bh, eoff, bsum, nscan, buf0, N);
    k_scan2<<<1, SCAN_B, 0, stream>>>(bsum, nbs);
    k_scan3<<<cdiv(nscan + 1, SCAN_B), SCAN_B, 0, stream>>>(eoff, bsum, nscan, E);
    k_bscatter<<<GB, B, 0, stream>>>(src, dst, eoff, ebuf, E, NB, EPB);
    k_csr<<<NB, 1024, 0, stream>>>(ebuf, eoff, rpd, dis, esrcb, N, E, NB);

    // ---- layer 1: Hs1 = fp8((x@W1)*dis); a1 = bf16(relu(dis*sum + b1)) ----
    k_gemm_lds<128, false, 2><<<cdiv(N, 64), B, 0, stream>>>(x, W1, dis, buf0, N);
    k_agg<0><<<cdiv(N, 4), B, 0, stream>>>((const unsigned char*)buf0, dis, rpd, esrcb,
                                           b1, buf1, N);

    // ---- layer 2: Hs2 = fp8((a1@W2)*dis); a2s = bf16(relu(dis*sum+b2)*dis) ----
    k_gemm_lds<64, true, 4><<<cdiv(N, 64), B, 0, stream>>>(buf1, W2, dis, buf0, N);
    k_agg<1><<<cdiv(N, 4), B, 0, stream>>>((const unsigned char*)buf0, dis, rpd, esrcb,
                                           b2, buf1, N);

    // ---- layer 3: z = fp8(a2s @ W3) (64 B rows); out = lsm gather ----
    const int NW = 8192;                      // 2048 blocks x 4 waves
    const int npw = cdiv(N, NW);
    k_zgemm<<<NW / 4, B, 0, stream>>>((const unsigned short*)buf1, W3,
                                      (unsigned char*)buf0, N, npw);
    k_aggz<<<cdiv(N, 4), B, 0, stream>>>((const unsigned char*)buf0, dis, rpd, esrcb,
                                         b3, out, N);
}

// Round 13
// 280.977 us; speedup vs baseline: 1.1738x; 1.0868x over previous
//
#include <hip/hip_runtime.h>
#include <math.h>

// ---------------------------------------------------------------------------
// 3-layer GCN, CSR-gather formulation.
// Round 26: MFMA for the three dense GEMMs.
//   R25 verdict: fp8-z landed (aggz FETCH 69->49.5 MB, total 305 us, absmax
//   unchanged). Gathers now at the compulsory-line floor. Biggest non-floor
//   block = VALU GEMMs (~55-60 us; gemm128 alone >=21 us VALU-bound).
//   New k_mgemm template: 64-row tile, 4 waves x 4 col-blocks,
//   v_mfma_f32_16x16x32_bf16, W transposed bf16 in LDS (contiguous B frags),
//   X bf16 +8 pad (2-way bank alias = free). C/D map col=lane&15,
//   row=(lane>>4)*4+reg (m89-verified). Epilogue: *dis, fp8 byte store.
//   zgemm = same template, W3 zero-padded to 64 cols (pad bytes = 0x00).
// N=100000, E=1200000, F: 128 -> 64 -> 64 -> 40
// ---------------------------------------------------------------------------

static inline int cdiv(long a, int b) { return (int)((a + b - 1) / b); }

// ---- bf16 helpers (RNE) ----
__device__ __forceinline__ unsigned short f2bf(float f) {
    unsigned u = __float_as_uint(f);
    u += 0x7fffu + ((u >> 16) & 1u);
    return (unsigned short)(u >> 16);
}
__device__ __forceinline__ float bf2f(unsigned short b) {
    return __uint_as_float(((unsigned)b) << 16);
}

// ---- fp8 e4m3 (OCP) helpers via gfx950 HW cvt ----
typedef float floatx2 __attribute__((ext_vector_type(2)));
typedef short bf16x8  __attribute__((ext_vector_type(8)));
typedef float f32x4   __attribute__((ext_vector_type(4)));
__device__ __forceinline__ float4 fp8x4_f(unsigned u) {
    floatx2 lo = __builtin_amdgcn_cvt_pk_f32_fp8(u, false);  // bytes 0,1
    floatx2 hi = __builtin_amdgcn_cvt_pk_f32_fp8(u, true);   // bytes 2,3
    float4 r; r.x = lo[0]; r.y = lo[1]; r.z = hi[0]; r.w = hi[1];
    return r;
}
__device__ __forceinline__ unsigned char f_fp8(float v) {
    return (unsigned char)(__builtin_amdgcn_cvt_pk_fp8_f32(v, v, 0u, false) & 0xFFu);
}

// ---- radix-bucket CSR build ----
#define RSH 9
#define RNODES 512            // 1 << RSH nodes per bucket
#define GB 1024               // blocks in bucket-hist / bucket-scatter passes
#define NBMAX 256             // max buckets (N <= 131072)
#define SMASK 0x1FFFF         // 17-bit src mask (N <= 131072)
#define PSLACK (RNODES * 16)  // per-bucket padding slack (8192 entries)

// K1: per-block bucket histogram (LDS atomics only).
__global__ __launch_bounds__(256)
void k_bhist(const int* __restrict__ dst, int* __restrict__ bh,
             int E, int NB, int EPB) {
    __shared__ int bcnt[NBMAX];
    const int tid = threadIdx.x, blk = blockIdx.x;
    for (int i = tid; i < NB; i += 256) bcnt[i] = 0;
    __syncthreads();
    const int e1 = min(E, (blk + 1) * EPB);
    for (int e = blk * EPB + tid; e < e1; e += 256)
        atomicAdd(&bcnt[dst[e] >> RSH], 1);
    __syncthreads();
    for (int i = tid; i < NB; i += 256) bh[i * GB + blk] = bcnt[i];
}

// K2: scatter edges into bucket-grouped ebuf (LDS cursors, no global atomics).
// Packed entry: (dst & 511) << 17 | src.
__global__ __launch_bounds__(256)
void k_bscatter(const int* __restrict__ src, const int* __restrict__ dst,
                const int* __restrict__ eoff, int* __restrict__ ebuf,
                int E, int NB, int EPB) {
    __shared__ int cur[NBMAX];
    const int tid = threadIdx.x, blk = blockIdx.x;
    for (int i = tid; i < NB; i += 256) cur[i] = eoff[i * GB + blk];
    __syncthreads();
    const int e1 = min(E, (blk + 1) * EPB);
    for (int e = blk * EPB + tid; e < e1; e += 256) {
        int d = dst[e];
        int s = src[e];
        int pos = atomicAdd(&cur[d >> RSH], 1);
        ebuf[pos] = ((d & (RNODES - 1)) << 17) | s;
    }
}

// K3: per-bucket CSR finalize -> PADDED esrcb (64 B-row byte offsets s<<6)
// + rpd + dis.  Per-node padded length = ceil(deg/16)*16; pads -> zero row N.
__global__ __launch_bounds__(1024)
void k_csr(const int* __restrict__ ebuf, const int* __restrict__ eoff,
           uint2* __restrict__ rpd, float* __restrict__ dis,
           unsigned int* __restrict__ esrcb, int N, int E, int NB) {
    __shared__ int cnt[RNODES];
    __shared__ int cur[RNODES];
    __shared__ int sm[1024];
    const int tid = threadIdx.x, b = blockIdx.x;
    const int node0 = b << RSH;
    const int bb = eoff[b * GB];
    const int be = (b + 1 == NB) ? E : eoff[(b + 1) * GB];
    const int pbase = ((bb + 15) & ~15) + b * PSLACK;   // 16-aligned

    if (tid < RNODES) cnt[tid] = 0;
    __syncthreads();
    for (int e = bb + tid; e < be; e += 1024)
        atomicAdd(&cnt[ebuf[e] >> 17], 1);
    __syncthreads();

    // exclusive scan of PADDED counts (window covers 0..511 for tid < 512)
    int v  = (tid < RNODES) ? cnt[tid] : 0;
    int pv = (v + 15) & ~15;
    sm[tid] = pv;
    __syncthreads();
    for (int off = 1; off < RNODES; off <<= 1) {
        int t = (tid >= off) ? sm[tid - off] : 0;
        __syncthreads();
        sm[tid] += t;
        __syncthreads();
    }
    if (tid < RNODES) {
        int excl = sm[tid] - pv;
        cur[tid] = pbase + excl;               // absolute padded cursor
        int node = node0 + tid;
        if (node < N) {
            rpd[node] = make_uint2((unsigned)(pbase + excl), (unsigned)((v + 15) >> 4));
            dis[node] = rsqrtf(1.0f + (float)v);   // +1 self-loop
        }
    }
    __syncthreads();
    const int ptot = sm[RNODES - 1];           // full-bucket padded total

    // pre-fill padded region with zero-row byte offset (stride 64 B: N<<6)
    const unsigned ZOFF = (unsigned)N << 6;
    for (int k = tid; k < ptot; k += 1024) esrcb[pbase + k] = ZOFF;
    __syncthreads();

    // rank-scatter real edges (64 B-row byte offsets s << 6)
    for (int e = bb + tid; e < be; e += 1024) {
        int ev = ebuf[e];
        int slot = atomicAdd(&cur[ev >> 17], 1);
        esrcb[slot] = (unsigned)(ev & SMASK) << 6;
    }
}

// ---- 3-step exclusive scan (for the [bucket][block] matrix) ----
#define SCAN_B 1024
// block 0 additionally zeroes the 64 B zero-row (row N of buf0).
__global__ void k_scan1(const int* __restrict__ cnt, int* __restrict__ rp,
                        int* __restrict__ bsum, int n, char* __restrict__ zbase,
                        int N) {
    __shared__ int sm[SCAN_B];
    const int tid = threadIdx.x;
    const int gid = blockIdx.x * SCAN_B + tid;
    if (blockIdx.x == 0 && tid < 16)
        ((unsigned*)(zbase + (size_t)N * 64))[tid] = 0;   // 16 x 4 B = 64 B
    int v = (gid < n) ? cnt[gid] : 0;
    sm[tid] = v;
    __syncthreads();
    for (int off = 1; off < SCAN_B; off <<= 1) {
        int t = (tid >= off) ? sm[tid - off] : 0;
        __syncthreads();
        sm[tid] += t;
        __syncthreads();
    }
    if (gid < n) rp[gid] = sm[tid] - v;           // exclusive
    if (tid == SCAN_B - 1) bsum[blockIdx.x] = sm[tid];
}

__global__ void k_scan2(int* __restrict__ bsum, int nb) {
    __shared__ int sm[SCAN_B];
    const int tid = threadIdx.x;
    int v = (tid < nb) ? bsum[tid] : 0;
    sm[tid] = v;
    __syncthreads();
    for (int off = 1; off < SCAN_B; off <<= 1) {
        int t = (tid >= off) ? sm[tid - off] : 0;
        __syncthreads();
        sm[tid] += t;
        __syncthreads();
    }
    if (tid < nb) bsum[tid] = sm[tid] - v;        // exclusive
}

__global__ void k_scan3(int* __restrict__ rp, const int* __restrict__ bsum, int n, int E) {
    const int gid = blockIdx.x * SCAN_B + threadIdx.x;
    if (gid < n) rp[gid] += bsum[gid / SCAN_B];
    if (gid == n) rp[n] = E;
}

// MFMA GEMM: out[N][64] fp8 = fp8( (X[N][K] @ W[K][WCOLS->64]) * (DIS?dis:1) )
// 64-row tile, 4 waves: wave w owns rows w*16..+15, 4 col-blocks of 16.
// X staged bf16 [64][K+8] (pad -> 2-way bank alias, free); W staged
// TRANSPOSED bf16 [64][K+8] so B-fragments are contiguous ds_read_b128.
// Fragment maps (v_mfma_f32_16x16x32_bf16): A row=l&15, k=(l>>4)*8+j;
// B col=l&15, same k; D col=l&15, row=(l>>4)*4+reg (m89-verified).
template<int K, bool BF16IN, int WCOLS, bool DIS>
__global__ __launch_bounds__(256, 4)
void k_mgemm(const void* __restrict__ Xv, const float* __restrict__ W,
             const float* __restrict__ dis, unsigned char* __restrict__ Hout, int N) {
    constexpr int KP = K + 8;                 // padded bf16 row stride
    __shared__ short xs[64 * KP];
    __shared__ short wt[64 * KP];
    const int tid = threadIdx.x;
    const int wv  = tid >> 6;                 // wave 0..3
    const int l   = tid & 63;
    const int row0 = blockIdx.x * 64;

    // stage Wt (transposed, bf16; cols >= WCOLS are zero)
    for (int idx = tid; idx < K * 64; idx += 256) {
        int k = idx >> 6, n = idx & 63;
        float v;
        if (WCOLS == 64) v = W[k * 64 + n];
        else             v = (n < WCOLS) ? W[k * WCOLS + n] : 0.f;
        wt[n * KP + k] = (short)f2bf(v);
    }
    // stage X tile (row-clamped), bf16
    if (BF16IN) {
        constexpr int C4 = K / 4;
        for (int idx = tid; idx < 64 * C4; idx += 256) {
            int r = idx / C4, c = idx % C4;
            int gr = min(row0 + r, N - 1);
            ushort4 u = *(const ushort4*)((const unsigned short*)Xv + (size_t)gr * K + c * 4);
            *(ushort4*)(&xs[r * KP + c * 4]) = u;
        }
    } else {
        constexpr int C4 = K / 4;
        for (int idx = tid; idx < 64 * C4; idx += 256) {
            int r = idx / C4, c = idx % C4;
            int gr = min(row0 + r, N - 1);
            float4 v = *(const float4*)((const float*)Xv + (size_t)gr * K + c * 4);
            ushort4 u;
            u.x = f2bf(v.x); u.y = f2bf(v.y); u.z = f2bf(v.z); u.w = f2bf(v.w);
            *(ushort4*)(&xs[r * KP + c * 4]) = u;
        }
    }
    __syncthreads();

    f32x4 acc0 = {0.f, 0.f, 0.f, 0.f};
    f32x4 acc1 = {0.f, 0.f, 0.f, 0.f};
    f32x4 acc2 = {0.f, 0.f, 0.f, 0.f};
    f32x4 acc3 = {0.f, 0.f, 0.f, 0.f};
    const int arow = wv * 16 + (l & 15);
    const int koffl = (l >> 4) * 8;

#pragma unroll
    for (int ks = 0; ks < K; ks += 32) {
        bf16x8 a  = *(const bf16x8*)(&xs[arow * KP + ks + koffl]);
        bf16x8 b0 = *(const bf16x8*)(&wt[( 0 + (l & 15)) * KP + ks + koffl]);
        bf16x8 b1 = *(const bf16x8*)(&wt[(16 + (l & 15)) * KP + ks + koffl]);
        bf16x8 b2 = *(const bf16x8*)(&wt[(32 + (l & 15)) * KP + ks + koffl]);
        bf16x8 b3 = *(const bf16x8*)(&wt[(48 + (l & 15)) * KP + ks + koffl]);
        acc0 = __builtin_amdgcn_mfma_f32_16x16x32_bf16(a, b0, acc0, 0, 0, 0);
        acc1 = __builtin_amdgcn_mfma_f32_16x16x32_bf16(a, b1, acc1, 0, 0, 0);
        acc2 = __builtin_amdgcn_mfma_f32_16x16x32_bf16(a, b2, acc2, 0, 0, 0);
        acc3 = __builtin_amdgcn_mfma_f32_16x16x32_bf16(a, b3, acc3, 0, 0, 0);
    }

    // epilogue: D col = l&15, row = (l>>4)*4 + j within the wave's 16-row slice
#pragma unroll
    for (int j = 0; j < 4; ++j) {
        int r = row0 + wv * 16 + ((l >> 4) << 2) + j;
        if (r < N) {
            float dd = DIS ? dis[r] : 1.0f;
            unsigned char* rowp = Hout + (size_t)r * 64 + (l & 15);
            rowp[0]  = f_fp8(acc0[j] * dd);
            rowp[16] = f_fp8(acc1[j] * dd);
            rowp[32] = f_fp8(acc2[j] * dd);
            rowp[48] = f_fp8(acc3[j] * dd);
        }
    }
}

// Wave-per-node segmented row-sum over padded CSR, fp8 rows (64 B, 1 line).
// Quad q reads 4 consecutive edges via one uint4; lane covers 4 features (4 B).
// MODE 0: A = relu(t + bias)           -> bf16  (a1, gemm64 input)
// MODE 1: A = relu(t + bias) * dis[d]  -> bf16  (a2s, zgemm input)
template<int MODE>
__global__ __launch_bounds__(256, 8)
void k_agg(const unsigned char* __restrict__ Hs8, const float* __restrict__ dis,
           const uint2* __restrict__ rpd, const unsigned int* __restrict__ esrcb,
           const float* __restrict__ bias, void* __restrict__ A, int N) {
    const int wave = threadIdx.x >> 6;
    const int lane = threadIdx.x & 63;
    const int node = blockIdx.x * (blockDim.x >> 6) + wave;
    if (node >= N) return;
    const int q    = lane >> 4;        // quad 0..3 -> 4 consecutive edges each
    const unsigned foff = (lane & 15) * 4;   // byte offset within 64 B fp8 row

    const uint2 pd = rpd[node];
    const char* base = (const char*)Hs8;
    float4 acc = {0.f, 0.f, 0.f, 0.f};
    unsigned e = pd.x + q * 4;
    for (unsigned it = 0; it < pd.y; ++it, e += 16) {
        uint4 ov = *(const uint4*)(esrcb + e);
        unsigned u0 = *(const unsigned*)(base + (ov.x + foff));
        unsigned u1 = *(const unsigned*)(base + (ov.y + foff));
        unsigned u2 = *(const unsigned*)(base + (ov.z + foff));
        unsigned u3 = *(const unsigned*)(base + (ov.w + foff));
        float4 h0 = fp8x4_f(u0);
        float4 h1 = fp8x4_f(u1);
        float4 h2 = fp8x4_f(u2);
        float4 h3 = fp8x4_f(u3);
        acc.x += (h0.x + h1.x) + (h2.x + h3.x);
        acc.y += (h0.y + h1.y) + (h2.y + h3.y);
        acc.z += (h0.z + h1.z) + (h2.z + h3.z);
        acc.w += (h0.w + h1.w) + (h2.w + h3.w);
    }
    // cross-quad reduce (after: lanes 0..15 hold the full row sum)
    acc.x += __shfl_xor(acc.x, 16, 64);
    acc.y += __shfl_xor(acc.y, 16, 64);
    acc.z += __shfl_xor(acc.z, 16, 64);
    acc.w += __shfl_xor(acc.w, 16, 64);
    acc.x += __shfl_xor(acc.x, 32, 64);
    acc.y += __shfl_xor(acc.y, 32, 64);
    acc.z += __shfl_xor(acc.z, 32, 64);
    acc.w += __shfl_xor(acc.w, 32, 64);

    if (lane < 16) {
        const float dd = dis[node];
        unsigned shv = *(const unsigned*)(Hs8 + (size_t)node * 64 + lane * 4);
        float4 sh = fp8x4_f(shv);
        float4 v;
        v.x = (acc.x + sh.x) * dd;
        v.y = (acc.y + sh.y) * dd;
        v.z = (acc.z + sh.z) * dd;
        v.w = (acc.w + sh.w) * dd;
        float4 bv = ((const float4*)bias)[lane];
        v.x = fmaxf(v.x + bv.x, 0.f);
        v.y = fmaxf(v.y + bv.y, 0.f);
        v.z = fmaxf(v.z + bv.z, 0.f);
        v.w = fmaxf(v.w + bv.w, 0.f);
        if (MODE == 1) {
            v.x *= dd; v.y *= dd; v.z *= dd; v.w *= dd;
        }
        ushort4 o;
        o.x = f2bf(v.x); o.y = f2bf(v.y); o.z = f2bf(v.z); o.w = f2bf(v.w);
        *(ushort4*)((unsigned short*)A + (size_t)node * 64 + lane * 4) = o;
    }
}

// Layer-3 gather + log_softmax over fp8 z rows (64 B, 1 line, 40 valid).
// Padded gather (esrcb s<<6 matches stride); wave-local shfl-only lsm.
__global__ __launch_bounds__(256, 8)
void k_aggz(const unsigned char* __restrict__ Z8, const float* __restrict__ dis,
            const uint2* __restrict__ rpd, const unsigned int* __restrict__ esrcb,
            const float* __restrict__ b3, float* __restrict__ out, int N) {
    const int wave = threadIdx.x >> 6;
    const int lane = threadIdx.x & 63;
    const int node = blockIdx.x * (blockDim.x >> 6) + wave;
    if (node >= N) return;
    const int q    = lane >> 4;
    const int f4   = lane & 15;
    const unsigned foff = f4 * 4;

    const uint2 pd = rpd[node];
    const char* base = (const char*)Z8;
    float4 acc = {0.f, 0.f, 0.f, 0.f};
    unsigned e = pd.x + q * 4;
    for (unsigned it = 0; it < pd.y; ++it, e += 16) {
        uint4 ov = *(const uint4*)(esrcb + e);
        unsigned u0 = *(const unsigned*)(base + (ov.x + foff));
        unsigned u1 = *(const unsigned*)(base + (ov.y + foff));
        unsigned u2 = *(const unsigned*)(base + (ov.z + foff));
        unsigned u3 = *(const unsigned*)(base + (ov.w + foff));
        float4 h0 = fp8x4_f(u0);
        float4 h1 = fp8x4_f(u1);
        float4 h2 = fp8x4_f(u2);
        float4 h3 = fp8x4_f(u3);
        acc.x += (h0.x + h1.x) + (h2.x + h3.x);
        acc.y += (h0.y + h1.y) + (h2.y + h3.y);
        acc.z += (h0.z + h1.z) + (h2.z + h3.z);
        acc.w += (h0.w + h1.w) + (h2.w + h3.w);
    }
    // cross-quad reduce: f4 preserved by xor 16/32 (q bits only)
    acc.x += __shfl_xor(acc.x, 16, 64);
    acc.y += __shfl_xor(acc.y, 16, 64);
    acc.z += __shfl_xor(acc.z, 16, 64);
    acc.w += __shfl_xor(acc.w, 16, 64);
    acc.x += __shfl_xor(acc.x, 32, 64);
    acc.y += __shfl_xor(acc.y, 32, 64);
    acc.z += __shfl_xor(acc.z, 32, 64);
    acc.w += __shfl_xor(acc.w, 32, 64);

    // wave-local log-softmax over features 0..39 (f4 < 10)
    const float dd = dis[node];
    unsigned shv = *(const unsigned*)(Z8 + (size_t)node * 64 + f4 * 4);
    float4 sh = fp8x4_f(shv);
    float4 bv = {0.f, 0.f, 0.f, 0.f};
    if (f4 < 10) bv = ((const float4*)b3)[f4];
    float4 v;
    v.x = (acc.x + sh.x) * dd + bv.x;
    v.y = (acc.y + sh.y) * dd + bv.y;
    v.z = (acc.z + sh.z) * dd + bv.z;
    v.w = (acc.w + sh.w) * dd + bv.w;

    float m = (f4 < 10) ? fmaxf(fmaxf(v.x, v.y), fmaxf(v.z, v.w)) : -INFINITY;
#pragma unroll
    for (int o = 1; o < 16; o <<= 1) m = fmaxf(m, __shfl_xor(m, o, 64));
    float es = (f4 < 10)
        ? expf(v.x - m) + expf(v.y - m) + expf(v.z - m) + expf(v.w - m) : 0.f;
#pragma unroll
    for (int o = 1; o < 16; o <<= 1) es += __shfl_xor(es, o, 64);

    if (lane < 10) {                   // q==0 && f4<10
        float ls = logf(es);
        float4 o4;
        o4.x = v.x - m - ls;
        o4.y = v.y - m - ls;
        o4.z = v.z - m - ls;
        o4.w = v.w - m - ls;
        *(float4*)(out + (size_t)node * 40 + lane * 4) = o4;
    }
}

extern "C" void kernel_launch(void* const* d_in, const int* in_sizes, int n_in,
                              void* d_out, int out_size, void* d_ws, size_t ws_size,
                              hipStream_t stream) {
    const float* x  = (const float*)d_in[0];
    const int*   ei = (const int*)d_in[1];
    const float* W1 = (const float*)d_in[2];
    const float* b1 = (const float*)d_in[3];
    const float* W2 = (const float*)d_in[4];
    const float* b2 = (const float*)d_in[5];
    const float* W3 = (const float*)d_in[6];
    const float* b3 = (const float*)d_in[7];
    float* out = (float*)d_out;

    const int N = in_sizes[0] / 128;
    const int E = in_sizes[1] / 2;
    const int* src = ei;
    const int* dst = ei + E;

    const int NB   = cdiv(N, RNODES);        // buckets (196 @ N=100000)
    const int EPB  = cdiv(E, GB);            // edges per hist/scatter block
    const int nscan = NB * GB;               // scan length (200704)
    const size_t esz = (size_t)E + (size_t)(NB + 2) * PSLACK + 64; // padded esrcb len

    // ---- workspace layout ----
    // buf0 (64 B rows + zero row N): Hs1 fp8 -> Hs2 fp8 -> z fp8
    // buf1: a1 bf16 -> a2s bf16 (128 B rows)
    char* ws = (char*)d_ws;
    char* buf0  = ws;                         ws += (size_t)(N + 1) * 64;           // 6.4 MB
    char* buf1  = ws;                         ws += (size_t)N * 128;                // 12.8 MB
    unsigned* esrcb = (unsigned*)ws;          ws += esz * sizeof(int);              // ~11.3 MB
    uint2* rpd  = (uint2*)ws;                 ws += (size_t)N * sizeof(uint2);      // 800 KB
    int*   bsum  = (int*)ws;                  ws += (size_t)SCAN_B * sizeof(int);
    float* dis   = (float*)ws;                ws += (size_t)N * sizeof(float);
    int*   bh    = (int*)ws;                  ws += (size_t)nscan * sizeof(int);    // 803 KB
    int*   eoff  = (int*)ws;                  ws += (size_t)(nscan + 1) * sizeof(int);
    int*   ebuf  = (int*)(ws);                ws += (size_t)E * sizeof(int);        // 4.8 MB

    const int B = 256;
    const int nbs = cdiv(nscan, SCAN_B);
    const int ngb = cdiv(N, 64);              // mgemm blocks

    // ---- CSR build: two-level counting sort, zero global atomics ----
    k_bhist<<<GB, B, 0, stream>>>(dst, bh, E, NB, EPB);
    k_scan1<<<nbs, SCAN_B, 0, stream>>>(bh, eoff, bsum, nscan, buf0, N);
    k_scan2<<<1, SCAN_B, 0, stream>>>(bsum, nbs);
    k_scan3<<<cdiv(nscan + 1, SCAN_B), SCAN_B, 0, stream>>>(eoff, bsum, nscan, E);
    k_bscatter<<<GB, B, 0, stream>>>(src, dst, eoff, ebuf, E, NB, EPB);
    k_csr<<<NB, 1024, 0, stream>>>(ebuf, eoff, rpd, dis, esrcb, N, E, NB);

    // ---- layer 1: Hs1 = fp8((x@W1)*dis); a1 = bf16(relu(dis*sum + b1)) ----
    k_mgemm<128, false, 64, true><<<ngb, B, 0, stream>>>(x, W1, dis,
                                                         (unsigned char*)buf0, N);
    k_agg<0><<<cdiv(N, 4), B, 0, stream>>>((const unsigned char*)buf0, dis, rpd, esrcb,
                                           b1, buf1, N);

    // ---- layer 2: Hs2 = fp8((a1@W2)*dis); a2s = bf16(relu(dis*sum+b2)*dis) ----
    k_mgemm<64, true, 64, true><<<ngb, B, 0, stream>>>(buf1, W2, dis,
                                                       (unsigned char*)buf0, N);
    k_agg<1><<<cdiv(N, 4), B, 0, stream>>>((const unsigned char*)buf0, dis, rpd, esrcb,
                                           b2, buf1, N);

    // ---- layer 3: z = fp8(a2s @ W3) (64 B rows, cols 40-63 = 0); lsm gather ----
    k_mgemm<64, true, 40, false><<<ngb, B, 0, stream>>>(buf1, W3, dis,
                                                        (unsigned char*)buf0, N);
    k_aggz<<<cdiv(N, 4), B, 0, stream>>>((const unsigned char*)buf0, dis, rpd, esrcb,
                                         b3, out, N);
}

// Round 14
// 280.756 us; speedup vs baseline: 1.1747x; 1.0008x over previous
//
#include <hip/hip_runtime.h>
#include <math.h>

// ---------------------------------------------------------------------------
// 3-layer GCN, CSR-gather formulation.
// Round 27: VALU-packed gathers + leaner k_csr.
//   R26 verdict: MFMA GEMMs landed (305->281). k_aggz now runs BELOW the
//   1.5 TB/s fill floor (1.16 TB/s) at VALUBusy ~70% => gathers flipped to
//   VALU-bound. (1) Accumulate as 2x floatx2 (+= cvt_pk result directly ->
//   v_pk_add_f32): 8 cvt + 8 pk-adds per 4 edges vs 8 cvt + 16 adds.
//   (2) k_csr: stage bucket's ebuf in LDS (single global pass; <=12288
//   entries, uniform fallback) and fill ONLY pad slots post-scatter
//   (~2.3 MB) instead of prefilling the whole padded region (11.3 MB).
// N=100000, E=1200000, F: 128 -> 64 -> 64 -> 40
// ---------------------------------------------------------------------------

static inline int cdiv(long a, int b) { return (int)((a + b - 1) / b); }

// ---- bf16 helpers (RNE) ----
__device__ __forceinline__ unsigned short f2bf(float f) {
    unsigned u = __float_as_uint(f);
    u += 0x7fffu + ((u >> 16) & 1u);
    return (unsigned short)(u >> 16);
}
__device__ __forceinline__ float bf2f(unsigned short b) {
    return __uint_as_float(((unsigned)b) << 16);
}

// ---- fp8 e4m3 (OCP) helpers via gfx950 HW cvt ----
typedef float floatx2 __attribute__((ext_vector_type(2)));
typedef short bf16x8  __attribute__((ext_vector_type(8)));
typedef float f32x4   __attribute__((ext_vector_type(4)));
__device__ __forceinline__ float4 fp8x4_f(unsigned u) {
    floatx2 lo = __builtin_amdgcn_cvt_pk_f32_fp8(u, false);  // bytes 0,1
    floatx2 hi = __builtin_amdgcn_cvt_pk_f32_fp8(u, true);   // bytes 2,3
    float4 r; r.x = lo[0]; r.y = lo[1]; r.z = hi[0]; r.w = hi[1];
    return r;
}
__device__ __forceinline__ unsigned char f_fp8(float v) {
    return (unsigned char)(__builtin_amdgcn_cvt_pk_fp8_f32(v, v, 0u, false) & 0xFFu);
}

// ---- radix-bucket CSR build ----
#define RSH 9
#define RNODES 512            // 1 << RSH nodes per bucket
#define GB 1024               // blocks in bucket-hist / bucket-scatter passes
#define NBMAX 256             // max buckets (N <= 131072)
#define SMASK 0x1FFFF         // 17-bit src mask (N <= 131072)
#define PSLACK (RNODES * 16)  // per-bucket padding slack (8192 entries)
#define EBMAX 12288           // LDS-staged bucket edge cap (48 KB)

// K1: per-block bucket histogram (LDS atomics only).
__global__ __launch_bounds__(256)
void k_bhist(const int* __restrict__ dst, int* __restrict__ bh,
             int E, int NB, int EPB) {
    __shared__ int bcnt[NBMAX];
    const int tid = threadIdx.x, blk = blockIdx.x;
    for (int i = tid; i < NB; i += 256) bcnt[i] = 0;
    __syncthreads();
    const int e1 = min(E, (blk + 1) * EPB);
    for (int e = blk * EPB + tid; e < e1; e += 256)
        atomicAdd(&bcnt[dst[e] >> RSH], 1);
    __syncthreads();
    for (int i = tid; i < NB; i += 256) bh[i * GB + blk] = bcnt[i];
}

// K2: scatter edges into bucket-grouped ebuf (LDS cursors, no global atomics).
// Packed entry: (dst & 511) << 17 | src.
__global__ __launch_bounds__(256)
void k_bscatter(const int* __restrict__ src, const int* __restrict__ dst,
                const int* __restrict__ eoff, int* __restrict__ ebuf,
                int E, int NB, int EPB) {
    __shared__ int cur[NBMAX];
    const int tid = threadIdx.x, blk = blockIdx.x;
    for (int i = tid; i < NB; i += 256) cur[i] = eoff[i * GB + blk];
    __syncthreads();
    const int e1 = min(E, (blk + 1) * EPB);
    for (int e = blk * EPB + tid; e < e1; e += 256) {
        int d = dst[e];
        int s = src[e];
        int pos = atomicAdd(&cur[d >> RSH], 1);
        ebuf[pos] = ((d & (RNODES - 1)) << 17) | s;
    }
}

// K3: per-bucket CSR finalize -> PADDED esrcb (64 B-row byte offsets s<<6)
// + rpd + dis. LDS-staged ebuf (single global read); pads-only fill.
__global__ __launch_bounds__(1024)
void k_csr(const int* __restrict__ ebuf, const int* __restrict__ eoff,
           uint2* __restrict__ rpd, float* __restrict__ dis,
           unsigned int* __restrict__ esrcb, int N, int E, int NB) {
    __shared__ int cnt[RNODES];
    __shared__ int cur[RNODES];
    __shared__ int sm[1024];
    __shared__ int esm[EBMAX];
    const int tid = threadIdx.x, b = blockIdx.x;
    const int node0 = b << RSH;
    const int bb = eoff[b * GB];
    const int be = (b + 1 == NB) ? E : eoff[(b + 1) * GB];
    const int nedge = be - bb;
    const bool inlds = (nedge <= EBMAX);       // block-uniform
    const int pbase = ((bb + 15) & ~15) + b * PSLACK;   // 16-aligned

    if (tid < RNODES) cnt[tid] = 0;
    if (inlds) {
        for (int e = tid; e < nedge; e += 1024) esm[e] = ebuf[bb + e];
    }
    __syncthreads();
    for (int e = tid; e < nedge; e += 1024)
        atomicAdd(&cnt[(inlds ? esm[e] : ebuf[bb + e]) >> 17], 1);
    __syncthreads();

    // exclusive scan of PADDED counts (window covers 0..511 for tid < 512)
    int v  = (tid < RNODES) ? cnt[tid] : 0;
    int pv = (v + 15) & ~15;
    sm[tid] = pv;
    __syncthreads();
    for (int off = 1; off < RNODES; off <<= 1) {
        int t = (tid >= off) ? sm[tid - off] : 0;
        __syncthreads();
        sm[tid] += t;
        __syncthreads();
    }
    if (tid < RNODES) {
        int excl = sm[tid] - pv;
        cur[tid] = pbase + excl;               // absolute padded cursor
        int node = node0 + tid;
        if (node < N) {
            rpd[node] = make_uint2((unsigned)(pbase + excl), (unsigned)((v + 15) >> 4));
            dis[node] = rsqrtf(1.0f + (float)v);   // +1 self-loop
        }
    }
    __syncthreads();

    // rank-scatter real edges (64 B-row byte offsets s << 6)
    for (int e = tid; e < nedge; e += 1024) {
        int ev = inlds ? esm[e] : ebuf[bb + e];
        int slot = atomicAdd(&cur[ev >> 17], 1);
        esrcb[slot] = (unsigned)(ev & SMASK) << 6;
    }
    __syncthreads();

    // fill ONLY the pad slots: [cur[tid] (= start+deg), pbase + sm[tid])
    const unsigned ZOFF = (unsigned)N << 6;
    if (tid < RNODES) {
        const int end = pbase + sm[tid];       // = start + padded_deg
        for (int k = cur[tid]; k < end; ++k) esrcb[k] = ZOFF;
    }
}

// ---- 3-step exclusive scan (for the [bucket][block] matrix) ----
#define SCAN_B 1024
// block 0 additionally zeroes the 64 B zero-row (row N of buf0).
__global__ void k_scan1(const int* __restrict__ cnt, int* __restrict__ rp,
                        int* __restrict__ bsum, int n, char* __restrict__ zbase,
                        int N) {
    __shared__ int sm[SCAN_B];
    const int tid = threadIdx.x;
    const int gid = blockIdx.x * SCAN_B + tid;
    if (blockIdx.x == 0 && tid < 16)
        ((unsigned*)(zbase + (size_t)N * 64))[tid] = 0;   // 16 x 4 B = 64 B
    int v = (gid < n) ? cnt[gid] : 0;
    sm[tid] = v;
    __syncthreads();
    for (int off = 1; off < SCAN_B; off <<= 1) {
        int t = (tid >= off) ? sm[tid - off] : 0;
        __syncthreads();
        sm[tid] += t;
        __syncthreads();
    }
    if (gid < n) rp[gid] = sm[tid] - v;           // exclusive
    if (tid == SCAN_B - 1) bsum[blockIdx.x] = sm[tid];
}

__global__ void k_scan2(int* __restrict__ bsum, int nb) {
    __shared__ int sm[SCAN_B];
    const int tid = threadIdx.x;
    int v = (tid < nb) ? bsum[tid] : 0;
    sm[tid] = v;
    __syncthreads();
    for (int off = 1; off < SCAN_B; off <<= 1) {
        int t = (tid >= off) ? sm[tid - off] : 0;
        __syncthreads();
        sm[tid] += t;
        __syncthreads();
    }
    if (tid < nb) bsum[tid] = sm[tid] - v;        // exclusive
}

__global__ void k_scan3(int* __restrict__ rp, const int* __restrict__ bsum, int n, int E) {
    const int gid = blockIdx.x * SCAN_B + threadIdx.x;
    if (gid < n) rp[gid] += bsum[gid / SCAN_B];
    if (gid == n) rp[n] = E;
}

// MFMA GEMM: out[N][64] fp8 = fp8( (X[N][K] @ W[K][WCOLS->64]) * (DIS?dis:1) )
// 64-row tile, 4 waves: wave w owns rows w*16..+15, 4 col-blocks of 16.
// X staged bf16 [64][K+8]; W staged TRANSPOSED bf16 [64][K+8].
// D map col=lane&15, row=(lane>>4)*4+reg (m89-verified).
template<int K, bool BF16IN, int WCOLS, bool DIS>
__global__ __launch_bounds__(256, 4)
void k_mgemm(const void* __restrict__ Xv, const float* __restrict__ W,
             const float* __restrict__ dis, unsigned char* __restrict__ Hout, int N) {
    constexpr int KP = K + 8;                 // padded bf16 row stride
    __shared__ short xs[64 * KP];
    __shared__ short wt[64 * KP];
    const int tid = threadIdx.x;
    const int wv  = tid >> 6;                 // wave 0..3
    const int l   = tid & 63;
    const int row0 = blockIdx.x * 64;

    // stage Wt (transposed, bf16; cols >= WCOLS are zero)
    for (int idx = tid; idx < K * 64; idx += 256) {
        int k = idx >> 6, n = idx & 63;
        float v;
        if (WCOLS == 64) v = W[k * 64 + n];
        else             v = (n < WCOLS) ? W[k * WCOLS + n] : 0.f;
        wt[n * KP + k] = (short)f2bf(v);
    }
    // stage X tile (row-clamped), bf16
    if (BF16IN) {
        constexpr int C4 = K / 4;
        for (int idx = tid; idx < 64 * C4; idx += 256) {
            int r = idx / C4, c = idx % C4;
            int gr = min(row0 + r, N - 1);
            ushort4 u = *(const ushort4*)((const unsigned short*)Xv + (size_t)gr * K + c * 4);
            *(ushort4*)(&xs[r * KP + c * 4]) = u;
        }
    } else {
        constexpr int C4 = K / 4;
        for (int idx = tid; idx < 64 * C4; idx += 256) {
            int r = idx / C4, c = idx % C4;
            int gr = min(row0 + r, N - 1);
            float4 v = *(const float4*)((const float*)Xv + (size_t)gr * K + c * 4);
            ushort4 u;
            u.x = f2bf(v.x); u.y = f2bf(v.y); u.z = f2bf(v.z); u.w = f2bf(v.w);
            *(ushort4*)(&xs[r * KP + c * 4]) = u;
        }
    }
    __syncthreads();

    f32x4 acc0 = {0.f, 0.f, 0.f, 0.f};
    f32x4 acc1 = {0.f, 0.f, 0.f, 0.f};
    f32x4 acc2 = {0.f, 0.f, 0.f, 0.f};
    f32x4 acc3 = {0.f, 0.f, 0.f, 0.f};
    const int arow = wv * 16 + (l & 15);
    const int koffl = (l >> 4) * 8;

#pragma unroll
    for (int ks = 0; ks < K; ks += 32) {
        bf16x8 a  = *(const bf16x8*)(&xs[arow * KP + ks + koffl]);
        bf16x8 b0 = *(const bf16x8*)(&wt[( 0 + (l & 15)) * KP + ks + koffl]);
        bf16x8 b1 = *(const bf16x8*)(&wt[(16 + (l & 15)) * KP + ks + koffl]);
        bf16x8 b2 = *(const bf16x8*)(&wt[(32 + (l & 15)) * KP + ks + koffl]);
        bf16x8 b3 = *(const bf16x8*)(&wt[(48 + (l & 15)) * KP + ks + koffl]);
        acc0 = __builtin_amdgcn_mfma_f32_16x16x32_bf16(a, b0, acc0, 0, 0, 0);
        acc1 = __builtin_amdgcn_mfma_f32_16x16x32_bf16(a, b1, acc1, 0, 0, 0);
        acc2 = __builtin_amdgcn_mfma_f32_16x16x32_bf16(a, b2, acc2, 0, 0, 0);
        acc3 = __builtin_amdgcn_mfma_f32_16x16x32_bf16(a, b3, acc3, 0, 0, 0);
    }

    // epilogue: D col = l&15, row = (l>>4)*4 + j within the wave's 16-row slice
#pragma unroll
    for (int j = 0; j < 4; ++j) {
        int r = row0 + wv * 16 + ((l >> 4) << 2) + j;
        if (r < N) {
            float dd = DIS ? dis[r] : 1.0f;
            unsigned char* rowp = Hout + (size_t)r * 64 + (l & 15);
            rowp[0]  = f_fp8(acc0[j] * dd);
            rowp[16] = f_fp8(acc1[j] * dd);
            rowp[32] = f_fp8(acc2[j] * dd);
            rowp[48] = f_fp8(acc3[j] * dd);
        }
    }
}

// Wave-per-node segmented row-sum over padded CSR, fp8 rows (64 B, 1 line).
// Packed accumulate: acc as 2x floatx2, += cvt_pk result (v_pk_add_f32).
// MODE 0: A = relu(t + bias)           -> bf16  (a1, gemm64 input)
// MODE 1: A = relu(t + bias) * dis[d]  -> bf16  (a2s, zgemm input)
template<int MODE>
__global__ __launch_bounds__(256, 8)
void k_agg(const unsigned char* __restrict__ Hs8, const float* __restrict__ dis,
           const uint2* __restrict__ rpd, const unsigned int* __restrict__ esrcb,
           const float* __restrict__ bias, void* __restrict__ A, int N) {
    const int wave = threadIdx.x >> 6;
    const int lane = threadIdx.x & 63;
    const int node = blockIdx.x * (blockDim.x >> 6) + wave;
    if (node >= N) return;
    const int q    = lane >> 4;        // quad 0..3 -> 4 consecutive edges each
    const unsigned foff = (lane & 15) * 4;   // byte offset within 64 B fp8 row

    const uint2 pd = rpd[node];
    const char* base = (const char*)Hs8;
    floatx2 aL = {0.f, 0.f};           // features 0,1 of the group
    floatx2 aH = {0.f, 0.f};           // features 2,3
    unsigned e = pd.x + q * 4;
    for (unsigned it = 0; it < pd.y; ++it, e += 16) {
        uint4 ov = *(const uint4*)(esrcb + e);
        unsigned u0 = *(const unsigned*)(base + (ov.x + foff));
        unsigned u1 = *(const unsigned*)(base + (ov.y + foff));
        unsigned u2 = *(const unsigned*)(base + (ov.z + foff));
        unsigned u3 = *(const unsigned*)(base + (ov.w + foff));
        aL += __builtin_amdgcn_cvt_pk_f32_fp8(u0, false);
        aH += __builtin_amdgcn_cvt_pk_f32_fp8(u0, true);
        aL += __builtin_amdgcn_cvt_pk_f32_fp8(u1, false);
        aH += __builtin_amdgcn_cvt_pk_f32_fp8(u1, true);
        aL += __builtin_amdgcn_cvt_pk_f32_fp8(u2, false);
        aH += __builtin_amdgcn_cvt_pk_f32_fp8(u2, true);
        aL += __builtin_amdgcn_cvt_pk_f32_fp8(u3, false);
        aH += __builtin_amdgcn_cvt_pk_f32_fp8(u3, true);
    }
    float4 acc; acc.x = aL[0]; acc.y = aL[1]; acc.z = aH[0]; acc.w = aH[1];
    // cross-quad reduce (after: lanes 0..15 hold the full row sum)
    acc.x += __shfl_xor(acc.x, 16, 64);
    acc.y += __shfl_xor(acc.y, 16, 64);
    acc.z += __shfl_xor(acc.z, 16, 64);
    acc.w += __shfl_xor(acc.w, 16, 64);
    acc.x += __shfl_xor(acc.x, 32, 64);
    acc.y += __shfl_xor(acc.y, 32, 64);
    acc.z += __shfl_xor(acc.z, 32, 64);
    acc.w += __shfl_xor(acc.w, 32, 64);

    if (lane < 16) {
        const float dd = dis[node];
        unsigned shv = *(const unsigned*)(Hs8 + (size_t)node * 64 + lane * 4);
        float4 sh = fp8x4_f(shv);
        float4 v;
        v.x = (acc.x + sh.x) * dd;
        v.y = (acc.y + sh.y) * dd;
        v.z = (acc.z + sh.z) * dd;
        v.w = (acc.w + sh.w) * dd;
        float4 bv = ((const float4*)bias)[lane];
        v.x = fmaxf(v.x + bv.x, 0.f);
        v.y = fmaxf(v.y + bv.y, 0.f);
        v.z = fmaxf(v.z + bv.z, 0.f);
        v.w = fmaxf(v.w + bv.w, 0.f);
        if (MODE == 1) {
            v.x *= dd; v.y *= dd; v.z *= dd; v.w *= dd;
        }
        ushort4 o;
        o.x = f2bf(v.x); o.y = f2bf(v.y); o.z = f2bf(v.z); o.w = f2bf(v.w);
        *(ushort4*)((unsigned short*)A + (size_t)node * 64 + lane * 4) = o;
    }
}

// Layer-3 gather + log_softmax over fp8 z rows (64 B, 1 line, 40 valid).
// Packed accumulate; wave-local shfl-only lsm epilogue.
__global__ __launch_bounds__(256, 8)
void k_aggz(const unsigned char* __restrict__ Z8, const float* __restrict__ dis,
            const uint2* __restrict__ rpd, const unsigned int* __restrict__ esrcb,
            const float* __restrict__ b3, float* __restrict__ out, int N) {
    const int wave = threadIdx.x >> 6;
    const int lane = threadIdx.x & 63;
    const int node = blockIdx.x * (blockDim.x >> 6) + wave;
    if (node >= N) return;
    const int q    = lane >> 4;
    const int f4   = lane & 15;
    const unsigned foff = f4 * 4;

    const uint2 pd = rpd[node];
    const char* base = (const char*)Z8;
    floatx2 aL = {0.f, 0.f};
    floatx2 aH = {0.f, 0.f};
    unsigned e = pd.x + q * 4;
    for (unsigned it = 0; it < pd.y; ++it, e += 16) {
        uint4 ov = *(const uint4*)(esrcb + e);
        unsigned u0 = *(const unsigned*)(base + (ov.x + foff));
        unsigned u1 = *(const unsigned*)(base + (ov.y + foff));
        unsigned u2 = *(const unsigned*)(base + (ov.z + foff));
        unsigned u3 = *(const unsigned*)(base + (ov.w + foff));
        aL += __builtin_amdgcn_cvt_pk_f32_fp8(u0, false);
        aH += __builtin_amdgcn_cvt_pk_f32_fp8(u0, true);
        aL += __builtin_amdgcn_cvt_pk_f32_fp8(u1, false);
        aH += __builtin_amdgcn_cvt_pk_f32_fp8(u1, true);
        aL += __builtin_amdgcn_cvt_pk_f32_fp8(u2, false);
        aH += __builtin_amdgcn_cvt_pk_f32_fp8(u2, true);
        aL += __builtin_amdgcn_cvt_pk_f32_fp8(u3, false);
        aH += __builtin_amdgcn_cvt_pk_f32_fp8(u3, true);
    }
    float4 acc; acc.x = aL[0]; acc.y = aL[1]; acc.z = aH[0]; acc.w = aH[1];
    // cross-quad reduce: f4 preserved by xor 16/32 (q bits only)
    acc.x += __shfl_xor(acc.x, 16, 64);
    acc.y += __shfl_xor(acc.y, 16, 64);
    acc.z += __shfl_xor(acc.z, 16, 64);
    acc.w += __shfl_xor(acc.w, 16, 64);
    acc.x += __shfl_xor(acc.x, 32, 64);
    acc.y += __shfl_xor(acc.y, 32, 64);
    acc.z += __shfl_xor(acc.z, 32, 64);
    acc.w += __shfl_xor(acc.w, 32, 64);

    // wave-local log-softmax over features 0..39 (f4 < 10)
    const float dd = dis[node];
    unsigned shv = *(const unsigned*)(Z8 + (size_t)node * 64 + f4 * 4);
    float4 sh = fp8x4_f(shv);
    float4 bv = {0.f, 0.f, 0.f, 0.f};
    if (f4 < 10) bv = ((const float4*)b3)[f4];
    float4 v;
    v.x = (acc.x + sh.x) * dd + bv.x;
    v.y = (acc.y + sh.y) * dd + bv.y;
    v.z = (acc.z + sh.z) * dd + bv.z;
    v.w = (acc.w + sh.w) * dd + bv.w;

    float m = (f4 < 10) ? fmaxf(fmaxf(v.x, v.y), fmaxf(v.z, v.w)) : -INFINITY;
#pragma unroll
    for (int o = 1; o < 16; o <<= 1) m = fmaxf(m, __shfl_xor(m, o, 64));
    float es = (f4 < 10)
        ? expf(v.x - m) + expf(v.y - m) + expf(v.z - m) + expf(v.w - m) : 0.f;
#pragma unroll
    for (int o = 1; o < 16; o <<= 1) es += __shfl_xor(es, o, 64);

    if (lane < 10) {                   // q==0 && f4<10
        float ls = logf(es);
        float4 o4;
        o4.x = v.x - m - ls;
        o4.y = v.y - m - ls;
        o4.z = v.z - m - ls;
        o4.w = v.w - m - ls;
        *(float4*)(out + (size_t)node * 40 + lane * 4) = o4;
    }
}

extern "C" void kernel_launch(void* const* d_in, const int* in_sizes, int n_in,
                              void* d_out, int out_size, void* d_ws, size_t ws_size,
                              hipStream_t stream) {
    const float* x  = (const float*)d_in[0];
    const int*   ei = (const int*)d_in[1];
    const float* W1 = (const float*)d_in[2];
    const float* b1 = (const float*)d_in[3];
    const float* W2 = (const float*)d_in[4];
    const float* b2 = (const float*)d_in[5];
    const float* W3 = (const float*)d_in[6];
    const float* b3 = (const float*)d_in[7];
    float* out = (float*)d_out;

    const int N = in_sizes[0] / 128;
    const int E = in_sizes[1] / 2;
    const int* src = ei;
    const int* dst = ei + E;

    const int NB   = cdiv(N, RNODES);        // buckets (196 @ N=100000)
    const int EPB  = cdiv(E, GB);            // edges per hist/scatter block
    const int nscan = NB * GB;               // scan length (200704)
    const size_t esz = (size_t)E + (size_t)(NB + 2) * PSLACK + 64; // padded esrcb len

    // ---- workspace layout ----
    // buf0 (64 B rows + zero row N): Hs1 fp8 -> Hs2 fp8 -> z fp8
    // buf1: a1 bf16 -> a2s bf16 (128 B rows)
    char* ws = (char*)d_ws;
    char* buf0  = ws;                         ws += (size_t)(N + 1) * 64;           // 6.4 MB
    char* buf1  = ws;                         ws += (size_t)N * 128;                // 12.8 MB
    unsigned* esrcb = (unsigned*)ws;          ws += esz * sizeof(int);              // ~11.3 MB
    uint2* rpd  = (uint2*)ws;                 ws += (size_t)N * sizeof(uint2);      // 800 KB
    int*   bsum  = (int*)ws;                  ws += (size_t)SCAN_B * sizeof(int);
    float* dis   = (float*)ws;                ws += (size_t)N * sizeof(float);
    int*   bh    = (int*)ws;                  ws += (size_t)nscan * sizeof(int);    // 803 KB
    int*   eoff  = (int*)ws;                  ws += (size_t)(nscan + 1) * sizeof(int);
    int*   ebuf  = (int*)(ws);                ws += (size_t)E * sizeof(int);        // 4.8 MB

    const int B = 256;
    const int nbs = cdiv(nscan, SCAN_B);
    const int ngb = cdiv(N, 64);              // mgemm blocks

    // ---- CSR build: two-level counting sort, zero global atomics ----
    k_bhist<<<GB, B, 0, stream>>>(dst, bh, E, NB, EPB);
    k_scan1<<<nbs, SCAN_B, 0, stream>>>(bh, eoff, bsum, nscan, buf0, N);
    k_scan2<<<1, SCAN_B, 0, stream>>>(bsum, nbs);
    k_scan3<<<cdiv(nscan + 1, SCAN_B), SCAN_B, 0, stream>>>(eoff, bsum, nscan, E);
    k_bscatter<<<GB, B, 0, stream>>>(src, dst, eoff, ebuf, E, NB, EPB);
    k_csr<<<NB, 1024, 0, stream>>>(ebuf, eoff, rpd, dis, esrcb, N, E, NB);

    // ---- layer 1: Hs1 = fp8((x@W1)*dis); a1 = bf16(relu(dis*sum + b1)) ----
    k_mgemm<128, false, 64, true><<<ngb, B, 0, stream>>>(x, W1, dis,
                                                         (unsigned char*)buf0, N);
    k_agg<0><<<cdiv(N, 4), B, 0, stream>>>((const unsigned char*)buf0, dis, rpd, esrcb,
                                           b1, buf1, N);

    // ---- layer 2: Hs2 = fp8((a1@W2)*dis); a2s = bf16(relu(dis*sum+b2)*dis) ----
    k_mgemm<64, true, 64, true><<<ngb, B, 0, stream>>>(buf1, W2, dis,
                                                       (unsigned char*)buf0, N);
    k_agg<1><<<cdiv(N, 4), B, 0, stream>>>((const unsigned char*)buf0, dis, rpd, esrcb,
                                           b2, buf1, N);

    // ---- layer 3: z = fp8(a2s @ W3) (64 B rows, cols 40-63 = 0); lsm gather ----
    k_mgemm<64, true, 40, false><<<ngb, B, 0, stream>>>(buf1, W3, dis,
                                                        (unsigned char*)buf0, N);
    k_aggz<<<cdiv(N, 4), B, 0, stream>>>((const unsigned char*)buf0, dis, rpd, esrcb,
                                         b3, out, N);
}

// Round 15
// 270.606 us; speedup vs baseline: 1.2188x; 1.0375x over previous
//
#include <hip/hip_runtime.h>
#include <math.h>

// ---------------------------------------------------------------------------
// 3-layer GCN, CSR-gather formulation.
// Round 28: CSR-chain trim + gather tail-latency hoist.
//   R27 verdict: packed adds flat -> gather loop body closed (~36/36/42 us).
//   (1) k_bscatter: per-block LDS counting-sort by bucket -> linear
//       piecewise-contiguous write-out (runs ~6) instead of 4B sprays
//       across 196 streams.
//   (2) k_scan3 deleted: GB==SCAN_B=1024 -> scan-block index of i*GB+blk
//       is exactly i; consumers add bsum[i] inline.
//   (3) k_agg/k_aggz: hoist dis/self-row/bias loads above the edge loop
//       (hide ~500cy under edge loads; waves are short, tails dominate).
// N=100000, E=1200000, F: 128 -> 64 -> 64 -> 40
// ---------------------------------------------------------------------------

static inline int cdiv(long a, int b) { return (int)((a + b - 1) / b); }

// ---- bf16 helpers (RNE) ----
__device__ __forceinline__ unsigned short f2bf(float f) {
    unsigned u = __float_as_uint(f);
    u += 0x7fffu + ((u >> 16) & 1u);
    return (unsigned short)(u >> 16);
}
__device__ __forceinline__ float bf2f(unsigned short b) {
    return __uint_as_float(((unsigned)b) << 16);
}

// ---- fp8 e4m3 (OCP) helpers via gfx950 HW cvt ----
typedef float floatx2 __attribute__((ext_vector_type(2)));
typedef short bf16x8  __attribute__((ext_vector_type(8)));
typedef float f32x4   __attribute__((ext_vector_type(4)));
__device__ __forceinline__ float4 fp8x4_f(unsigned u) {
    floatx2 lo = __builtin_amdgcn_cvt_pk_f32_fp8(u, false);  // bytes 0,1
    floatx2 hi = __builtin_amdgcn_cvt_pk_f32_fp8(u, true);   // bytes 2,3
    float4 r; r.x = lo[0]; r.y = lo[1]; r.z = hi[0]; r.w = hi[1];
    return r;
}
__device__ __forceinline__ unsigned char f_fp8(float v) {
    return (unsigned char)(__builtin_amdgcn_cvt_pk_fp8_f32(v, v, 0u, false) & 0xFFu);
}

// ---- radix-bucket CSR build ----
#define RSH 9
#define RNODES 512            // 1 << RSH nodes per bucket
#define GB 1024               // blocks in bucket-hist / bucket-scatter (== SCAN_B!)
#define NBMAX 256             // max buckets (N <= 131072)
#define SMASK 0x1FFFF         // 17-bit src mask (N <= 131072)
#define PSLACK (RNODES * 16)  // per-bucket padding slack (8192 entries)
#define EBMAX 12288           // LDS-staged bucket edge cap in k_csr (48 KB)
#define EPBS 1280             // bscatter chunk size (>= cdiv(E,GB))

// K1: per-block bucket histogram (LDS atomics only).
__global__ __launch_bounds__(256)
void k_bhist(const int* __restrict__ dst, int* __restrict__ bh,
             int E, int NB, int EPB) {
    __shared__ int bcnt[NBMAX];
    const int tid = threadIdx.x, blk = blockIdx.x;
    for (int i = tid; i < NB; i += 256) bcnt[i] = 0;
    __syncthreads();
    const int e1 = min(E, (blk + 1) * EPB);
    for (int e = blk * EPB + tid; e < e1; e += 256)
        atomicAdd(&bcnt[dst[e] >> RSH], 1);
    __syncthreads();
    for (int i = tid; i < NB; i += 256) bh[i * GB + blk] = bcnt[i];
}

// K2: LDS counting-sort by bucket, then linear (piecewise-contiguous) write.
// eoff holds scan1 partials; global base = eoff[i*GB+blk] + bsum[i].
__global__ __launch_bounds__(256)
void k_bscatter(const int* __restrict__ src, const int* __restrict__ dst,
                const int* __restrict__ eoff, const int* __restrict__ bsum,
                int* __restrict__ ebuf, int E, int NB, int EPB) {
    __shared__ int hist[NBMAX];
    __shared__ int lbase[NBMAX];
    __shared__ int lcur[NBMAX];
    __shared__ int gcur[NBMAX];
    __shared__ int sm[NBMAX];
    __shared__ int vals[EPBS];
    __shared__ int sorted[EPBS];
    __shared__ unsigned char bks[EPBS];
    __shared__ unsigned char sbk[EPBS];
    const int tid = threadIdx.x, blk = blockIdx.x;

    for (int i = tid; i < NBMAX; i += 256)
        gcur[i] = (i < NB) ? (eoff[i * GB + blk] + bsum[i]) : 0;

    const int e0 = blk * EPB;
    const int e1 = min(E, e0 + EPB);
    for (int ch = e0; ch < e1; ch += EPBS) {
        const int n = min(e1 - ch, EPBS);
        // phase A: load + per-chunk bucket histogram
        for (int i = tid; i < NBMAX; i += 256) hist[i] = 0;
        __syncthreads();
        for (int i = tid; i < n; i += 256) {
            int d = dst[ch + i];
            int s = src[ch + i];
            int bk = d >> RSH;
            vals[i] = ((d & (RNODES - 1)) << 17) | s;
            bks[i]  = (unsigned char)bk;
            atomicAdd(&hist[bk], 1);
        }
        __syncthreads();
        // phase B: exclusive scan of hist over 256 entries
        int hv = hist[tid];
        sm[tid] = hv;
        __syncthreads();
        for (int off = 1; off < NBMAX; off <<= 1) {
            int t = (tid >= off) ? sm[tid - off] : 0;
            __syncthreads();
            sm[tid] += t;
            __syncthreads();
        }
        lbase[tid] = sm[tid] - hv;
        lcur[tid] = 0;
        __syncthreads();
        // phase C: scatter into LDS-sorted order
        for (int i = tid; i < n; i += 256) {
            int bk = bks[i];
            int r = atomicAdd(&lcur[bk], 1);
            int p = lbase[bk] + r;
            sorted[p] = vals[i];
            sbk[p] = (unsigned char)bk;
        }
        __syncthreads();
        // phase D: linear write-out (dest runs are contiguous per bucket)
        for (int j = tid; j < n; j += 256) {
            int bk = sbk[j];
            ebuf[gcur[bk] + (j - lbase[bk])] = sorted[j];
        }
        __syncthreads();
        // advance global cursors
        for (int i = tid; i < NBMAX; i += 256) gcur[i] += hist[i];
        __syncthreads();
    }
}

// K3: per-bucket CSR finalize -> PADDED esrcb (64 B-row byte offsets s<<6)
// + rpd + dis. LDS-staged ebuf (single global read); pads-only fill.
__global__ __launch_bounds__(1024)
void k_csr(const int* __restrict__ ebuf, const int* __restrict__ eoff,
           const int* __restrict__ bsum,
           uint2* __restrict__ rpd, float* __restrict__ dis,
           unsigned int* __restrict__ esrcb, int N, int E, int NB) {
    __shared__ int cnt[RNODES];
    __shared__ int cur[RNODES];
    __shared__ int sm[1024];
    __shared__ int esm[EBMAX];
    const int tid = threadIdx.x, b = blockIdx.x;
    const int node0 = b << RSH;
    const int bb = eoff[b * GB] + bsum[b];
    const int be = (b + 1 == NB) ? E : (eoff[(b + 1) * GB] + bsum[b + 1]);
    const int nedge = be - bb;
    const bool inlds = (nedge <= EBMAX);       // block-uniform
    const int pbase = ((bb + 15) & ~15) + b * PSLACK;   // 16-aligned

    if (tid < RNODES) cnt[tid] = 0;
    if (inlds) {
        for (int e = tid; e < nedge; e += 1024) esm[e] = ebuf[bb + e];
    }
    __syncthreads();
    for (int e = tid; e < nedge; e += 1024)
        atomicAdd(&cnt[(inlds ? esm[e] : ebuf[bb + e]) >> 17], 1);
    __syncthreads();

    // exclusive scan of PADDED counts (window covers 0..511 for tid < 512)
    int v  = (tid < RNODES) ? cnt[tid] : 0;
    int pv = (v + 15) & ~15;
    sm[tid] = pv;
    __syncthreads();
    for (int off = 1; off < RNODES; off <<= 1) {
        int t = (tid >= off) ? sm[tid - off] : 0;
        __syncthreads();
        sm[tid] += t;
        __syncthreads();
    }
    if (tid < RNODES) {
        int excl = sm[tid] - pv;
        cur[tid] = pbase + excl;               // absolute padded cursor
        int node = node0 + tid;
        if (node < N) {
            rpd[node] = make_uint2((unsigned)(pbase + excl), (unsigned)((v + 15) >> 4));
            dis[node] = rsqrtf(1.0f + (float)v);   // +1 self-loop
        }
    }
    __syncthreads();

    // rank-scatter real edges (64 B-row byte offsets s << 6)
    for (int e = tid; e < nedge; e += 1024) {
        int ev = inlds ? esm[e] : ebuf[bb + e];
        int slot = atomicAdd(&cur[ev >> 17], 1);
        esrcb[slot] = (unsigned)(ev & SMASK) << 6;
    }
    __syncthreads();

    // fill ONLY the pad slots: [cur[tid] (= start+deg), pbase + sm[tid])
    const unsigned ZOFF = (unsigned)N << 6;
    if (tid < RNODES) {
        const int end = pbase + sm[tid];       // = start + padded_deg
        for (int k = cur[tid]; k < end; ++k) esrcb[k] = ZOFF;
    }
}

// ---- 2-step exclusive scan (partials + block sums; consumers add bsum) ----
#define SCAN_B 1024
// block 0 additionally zeroes the 64 B zero-row (row N of buf0).
__global__ void k_scan1(const int* __restrict__ cnt, int* __restrict__ rp,
                        int* __restrict__ bsum, int n, char* __restrict__ zbase,
                        int N) {
    __shared__ int sm[SCAN_B];
    const int tid = threadIdx.x;
    const int gid = blockIdx.x * SCAN_B + tid;
    if (blockIdx.x == 0 && tid < 16)
        ((unsigned*)(zbase + (size_t)N * 64))[tid] = 0;   // 16 x 4 B = 64 B
    int v = (gid < n) ? cnt[gid] : 0;
    sm[tid] = v;
    __syncthreads();
    for (int off = 1; off < SCAN_B; off <<= 1) {
        int t = (tid >= off) ? sm[tid - off] : 0;
        __syncthreads();
        sm[tid] += t;
        __syncthreads();
    }
    if (gid < n) rp[gid] = sm[tid] - v;           // exclusive partial
    if (tid == SCAN_B - 1) bsum[blockIdx.x] = sm[tid];
}

__global__ void k_scan2(int* __restrict__ bsum, int nb) {
    __shared__ int sm[SCAN_B];
    const int tid = threadIdx.x;
    int v = (tid < nb) ? bsum[tid] : 0;
    sm[tid] = v;
    __syncthreads();
    for (int off = 1; off < SCAN_B; off <<= 1) {
        int t = (tid >= off) ? sm[tid - off] : 0;
        __syncthreads();
        sm[tid] += t;
        __syncthreads();
    }
    if (tid < nb) bsum[tid] = sm[tid] - v;        // exclusive
}

// MFMA GEMM: out[N][64] fp8 = fp8( (X[N][K] @ W[K][WCOLS->64]) * (DIS?dis:1) )
// 64-row tile, 4 waves: wave w owns rows w*16..+15, 4 col-blocks of 16.
// X staged bf16 [64][K+8]; W staged TRANSPOSED bf16 [64][K+8].
// D map col=lane&15, row=(lane>>4)*4+reg (m89-verified).
template<int K, bool BF16IN, int WCOLS, bool DIS>
__global__ __launch_bounds__(256, 4)
void k_mgemm(const void* __restrict__ Xv, const float* __restrict__ W,
             const float* __restrict__ dis, unsigned char* __restrict__ Hout, int N) {
    constexpr int KP = K + 8;                 // padded bf16 row stride
    __shared__ short xs[64 * KP];
    __shared__ short wt[64 * KP];
    const int tid = threadIdx.x;
    const int wv  = tid >> 6;                 // wave 0..3
    const int l   = tid & 63;
    const int row0 = blockIdx.x * 64;

    // stage Wt (transposed, bf16; cols >= WCOLS are zero)
    for (int idx = tid; idx < K * 64; idx += 256) {
        int k = idx >> 6, n = idx & 63;
        float v;
        if (WCOLS == 64) v = W[k * 64 + n];
        else             v = (n < WCOLS) ? W[k * WCOLS + n] : 0.f;
        wt[n * KP + k] = (short)f2bf(v);
    }
    // stage X tile (row-clamped), bf16
    if (BF16IN) {
        constexpr int C4 = K / 4;
        for (int idx = tid; idx < 64 * C4; idx += 256) {
            int r = idx / C4, c = idx % C4;
            int gr = min(row0 + r, N - 1);
            ushort4 u = *(const ushort4*)((const unsigned short*)Xv + (size_t)gr * K + c * 4);
            *(ushort4*)(&xs[r * KP + c * 4]) = u;
        }
    } else {
        constexpr int C4 = K / 4;
        for (int idx = tid; idx < 64 * C4; idx += 256) {
            int r = idx / C4, c = idx % C4;
            int gr = min(row0 + r, N - 1);
            float4 v = *(const float4*)((const float*)Xv + (size_t)gr * K + c * 4);
            ushort4 u;
            u.x = f2bf(v.x); u.y = f2bf(v.y); u.z = f2bf(v.z); u.w = f2bf(v.w);
            *(ushort4*)(&xs[r * KP + c * 4]) = u;
        }
    }
    __syncthreads();

    f32x4 acc0 = {0.f, 0.f, 0.f, 0.f};
    f32x4 acc1 = {0.f, 0.f, 0.f, 0.f};
    f32x4 acc2 = {0.f, 0.f, 0.f, 0.f};
    f32x4 acc3 = {0.f, 0.f, 0.f, 0.f};
    const int arow = wv * 16 + (l & 15);
    const int koffl = (l >> 4) * 8;

#pragma unroll
    for (int ks = 0; ks < K; ks += 32) {
        bf16x8 a  = *(const bf16x8*)(&xs[arow * KP + ks + koffl]);
        bf16x8 b0 = *(const bf16x8*)(&wt[( 0 + (l & 15)) * KP + ks + koffl]);
        bf16x8 b1 = *(const bf16x8*)(&wt[(16 + (l & 15)) * KP + ks + koffl]);
        bf16x8 b2 = *(const bf16x8*)(&wt[(32 + (l & 15)) * KP + ks + koffl]);
        bf16x8 b3 = *(const bf16x8*)(&wt[(48 + (l & 15)) * KP + ks + koffl]);
        acc0 = __builtin_amdgcn_mfma_f32_16x16x32_bf16(a, b0, acc0, 0, 0, 0);
        acc1 = __builtin_amdgcn_mfma_f32_16x16x32_bf16(a, b1, acc1, 0, 0, 0);
        acc2 = __builtin_amdgcn_mfma_f32_16x16x32_bf16(a, b2, acc2, 0, 0, 0);
        acc3 = __builtin_amdgcn_mfma_f32_16x16x32_bf16(a, b3, acc3, 0, 0, 0);
    }

    // epilogue: D col = l&15, row = (l>>4)*4 + j within the wave's 16-row slice
#pragma unroll
    for (int j = 0; j < 4; ++j) {
        int r = row0 + wv * 16 + ((l >> 4) << 2) + j;
        if (r < N) {
            float dd = DIS ? dis[r] : 1.0f;
            unsigned char* rowp = Hout + (size_t)r * 64 + (l & 15);
            rowp[0]  = f_fp8(acc0[j] * dd);
            rowp[16] = f_fp8(acc1[j] * dd);
            rowp[32] = f_fp8(acc2[j] * dd);
            rowp[48] = f_fp8(acc3[j] * dd);
        }
    }
}

// Wave-per-node segmented row-sum over padded CSR, fp8 rows (64 B, 1 line).
// Epilogue loads (dis/self/bias) hoisted above the edge loop.
// MODE 0: A = relu(t + bias)           -> bf16  (a1, gemm64 input)
// MODE 1: A = relu(t + bias) * dis[d]  -> bf16  (a2s, zgemm input)
template<int MODE>
__global__ __launch_bounds__(256, 8)
void k_agg(const unsigned char* __restrict__ Hs8, const float* __restrict__ dis,
           const uint2* __restrict__ rpd, const unsigned int* __restrict__ esrcb,
           const float* __restrict__ bias, void* __restrict__ A, int N) {
    const int wave = threadIdx.x >> 6;
    const int lane = threadIdx.x & 63;
    const int node = blockIdx.x * (blockDim.x >> 6) + wave;
    if (node >= N) return;
    const int q    = lane >> 4;        // quad 0..3 -> 4 consecutive edges each
    const int f4   = lane & 15;
    const unsigned foff = f4 * 4;      // byte offset within 64 B fp8 row

    const uint2 pd = rpd[node];
    // hoisted epilogue loads (latency hides under the edge loop)
    const float dd = dis[node];
    unsigned shv = *(const unsigned*)(Hs8 + (size_t)node * 64 + foff);
    float4 bv = ((const float4*)bias)[f4];

    const char* base = (const char*)Hs8;
    floatx2 aL = {0.f, 0.f};           // features 0,1 of the group
    floatx2 aH = {0.f, 0.f};           // features 2,3
    unsigned e = pd.x + q * 4;
    for (unsigned it = 0; it < pd.y; ++it, e += 16) {
        uint4 ov = *(const uint4*)(esrcb + e);
        unsigned u0 = *(const unsigned*)(base + (ov.x + foff));
        unsigned u1 = *(const unsigned*)(base + (ov.y + foff));
        unsigned u2 = *(const unsigned*)(base + (ov.z + foff));
        unsigned u3 = *(const unsigned*)(base + (ov.w + foff));
        aL += __builtin_amdgcn_cvt_pk_f32_fp8(u0, false);
        aH += __builtin_amdgcn_cvt_pk_f32_fp8(u0, true);
        aL += __builtin_amdgcn_cvt_pk_f32_fp8(u1, false);
        aH += __builtin_amdgcn_cvt_pk_f32_fp8(u1, true);
        aL += __builtin_amdgcn_cvt_pk_f32_fp8(u2, false);
        aH += __builtin_amdgcn_cvt_pk_f32_fp8(u2, true);
        aL += __builtin_amdgcn_cvt_pk_f32_fp8(u3, false);
        aH += __builtin_amdgcn_cvt_pk_f32_fp8(u3, true);
    }
    float4 acc; acc.x = aL[0]; acc.y = aL[1]; acc.z = aH[0]; acc.w = aH[1];
    // cross-quad reduce (after: lanes 0..15 hold the full row sum)
    acc.x += __shfl_xor(acc.x, 16, 64);
    acc.y += __shfl_xor(acc.y, 16, 64);
    acc.z += __shfl_xor(acc.z, 16, 64);
    acc.w += __shfl_xor(acc.w, 16, 64);
    acc.x += __shfl_xor(acc.x, 32, 64);
    acc.y += __shfl_xor(acc.y, 32, 64);
    acc.z += __shfl_xor(acc.z, 32, 64);
    acc.w += __shfl_xor(acc.w, 32, 64);

    if (lane < 16) {
        float4 sh = fp8x4_f(shv);
        float4 v;
        v.x = (acc.x + sh.x) * dd;
        v.y = (acc.y + sh.y) * dd;
        v.z = (acc.z + sh.z) * dd;
        v.w = (acc.w + sh.w) * dd;
        v.x = fmaxf(v.x + bv.x, 0.f);
        v.y = fmaxf(v.y + bv.y, 0.f);
        v.z = fmaxf(v.z + bv.z, 0.f);
        v.w = fmaxf(v.w + bv.w, 0.f);
        if (MODE == 1) {
            v.x *= dd; v.y *= dd; v.z *= dd; v.w *= dd;
        }
        ushort4 o;
        o.x = f2bf(v.x); o.y = f2bf(v.y); o.z = f2bf(v.z); o.w = f2bf(v.w);
        *(ushort4*)((unsigned short*)A + (size_t)node * 64 + lane * 4) = o;
    }
}

// Layer-3 gather + log_softmax over fp8 z rows (64 B, 1 line, 40 valid).
// Hoisted epilogue loads; wave-local shfl-only lsm epilogue.
__global__ __launch_bounds__(256, 8)
void k_aggz(const unsigned char* __restrict__ Z8, const float* __restrict__ dis,
            const uint2* __restrict__ rpd, const unsigned int* __restrict__ esrcb,
            const float* __restrict__ b3, float* __restrict__ out, int N) {
    const int wave = threadIdx.x >> 6;
    const int lane = threadIdx.x & 63;
    const int node = blockIdx.x * (blockDim.x >> 6) + wave;
    if (node >= N) return;
    const int q    = lane >> 4;
    const int f4   = lane & 15;
    const unsigned foff = f4 * 4;

    const uint2 pd = rpd[node];
    // hoisted epilogue loads
    const float dd = dis[node];
    unsigned shv = *(const unsigned*)(Z8 + (size_t)node * 64 + foff);
    float4 bv = ((const float4*)b3)[min(f4, 9)];   // clamp: b3 has 10 float4s

    const char* base = (const char*)Z8;
    floatx2 aL = {0.f, 0.f};
    floatx2 aH = {0.f, 0.f};
    unsigned e = pd.x + q * 4;
    for (unsigned it = 0; it < pd.y; ++it, e += 16) {
        uint4 ov = *(const uint4*)(esrcb + e);
        unsigned u0 = *(const unsigned*)(base + (ov.x + foff));
        unsigned u1 = *(const unsigned*)(base + (ov.y + foff));
        unsigned u2 = *(const unsigned*)(base + (ov.z + foff));
        unsigned u3 = *(const unsigned*)(base + (ov.w + foff));
        aL += __builtin_amdgcn_cvt_pk_f32_fp8(u0, false);
        aH += __builtin_amdgcn_cvt_pk_f32_fp8(u0, true);
        aL += __builtin_amdgcn_cvt_pk_f32_fp8(u1, false);
        aH += __builtin_amdgcn_cvt_pk_f32_fp8(u1, true);
        aL += __builtin_amdgcn_cvt_pk_f32_fp8(u2, false);
        aH += __builtin_amdgcn_cvt_pk_f32_fp8(u2, true);
        aL += __builtin_amdgcn_cvt_pk_f32_fp8(u3, false);
        aH += __builtin_amdgcn_cvt_pk_f32_fp8(u3, true);
    }
    float4 acc; acc.x = aL[0]; acc.y = aL[1]; acc.z = aH[0]; acc.w = aH[1];
    // cross-quad reduce: f4 preserved by xor 16/32 (q bits only)
    acc.x += __shfl_xor(acc.x, 16, 64);
    acc.y += __shfl_xor(acc.y, 16, 64);
    acc.z += __shfl_xor(acc.z, 16, 64);
    acc.w += __shfl_xor(acc.w, 16, 64);
    acc.x += __shfl_xor(acc.x, 32, 64);
    acc.y += __shfl_xor(acc.y, 32, 64);
    acc.z += __shfl_xor(acc.z, 32, 64);
    acc.w += __shfl_xor(acc.w, 32, 64);

    // wave-local log-softmax over features 0..39 (f4 < 10)
    float4 sh = fp8x4_f(shv);
    float4 v;
    v.x = (acc.x + sh.x) * dd + bv.x;
    v.y = (acc.y + sh.y) * dd + bv.y;
    v.z = (acc.z + sh.z) * dd + bv.z;
    v.w = (acc.w + sh.w) * dd + bv.w;

    float m = (f4 < 10) ? fmaxf(fmaxf(v.x, v.y), fmaxf(v.z, v.w)) : -INFINITY;
#pragma unroll
    for (int o = 1; o < 16; o <<= 1) m = fmaxf(m, __shfl_xor(m, o, 64));
    float es = (f4 < 10)
        ? expf(v.x - m) + expf(v.y - m) + expf(v.z - m) + expf(v.w - m) : 0.f;
#pragma unroll
    for (int o = 1; o < 16; o <<= 1) es += __shfl_xor(es, o, 64);

    if (lane < 10) {                   // q==0 && f4<10
        float ls = logf(es);
        float4 o4;
        o4.x = v.x - m - ls;
        o4.y = v.y - m - ls;
        o4.z = v.z - m - ls;
        o4.w = v.w - m - ls;
        *(float4*)(out + (size_t)node * 40 + lane * 4) = o4;
    }
}

extern "C" void kernel_launch(void* const* d_in, const int* in_sizes, int n_in,
                              void* d_out, int out_size, void* d_ws, size_t ws_size,
                              hipStream_t stream) {
    const float* x  = (const float*)d_in[0];
    const int*   ei = (const int*)d_in[1];
    const float* W1 = (const float*)d_in[2];
    const float* b1 = (const float*)d_in[3];
    const float* W2 = (const float*)d_in[4];
    const float* b2 = (const float*)d_in[5];
    const float* W3 = (const float*)d_in[6];
    const float* b3 = (const float*)d_in[7];
    float* out = (float*)d_out;

    const int N = in_sizes[0] / 128;
    const int E = in_sizes[1] / 2;
    const int* src = ei;
    const int* dst = ei + E;

    const int NB   = cdiv(N, RNODES);        // buckets (196 @ N=100000)
    const int EPB  = cdiv(E, GB);            // edges per hist/scatter block (1172)
    const int nscan = NB * GB;               // scan length (200704)
    const size_t esz = (size_t)E + (size_t)(NB + 2) * PSLACK + 64; // padded esrcb len

    // ---- workspace layout ----
    // buf0 (64 B rows + zero row N): Hs1 fp8 -> Hs2 fp8 -> z fp8
    // buf1: a1 bf16 -> a2s bf16 (128 B rows)
    char* ws = (char*)d_ws;
    char* buf0  = ws;                         ws += (size_t)(N + 1) * 64;           // 6.4 MB
    char* buf1  = ws;                         ws += (size_t)N * 128;                // 12.8 MB
    unsigned* esrcb = (unsigned*)ws;          ws += esz * sizeof(int);              // ~11.3 MB
    uint2* rpd  = (uint2*)ws;                 ws += (size_t)N * sizeof(uint2);      // 800 KB
    int*   bsum  = (int*)ws;                  ws += (size_t)SCAN_B * sizeof(int);
    float* dis   = (float*)ws;                ws += (size_t)N * sizeof(float);
    int*   bh    = (int*)ws;                  ws += (size_t)nscan * sizeof(int);    // 803 KB
    int*   eoff  = (int*)ws;                  ws += (size_t)(nscan + 1) * sizeof(int);
    int*   ebuf  = (int*)(ws);                ws += (size_t)E * sizeof(int);        // 4.8 MB

    const int B = 256;
    const int nbs = cdiv(nscan, SCAN_B);      // 196 (GB == SCAN_B)
    const int ngb = cdiv(N, 64);              // mgemm blocks

    // ---- CSR build: two-level counting sort, zero global atomics ----
    k_bhist<<<GB, B, 0, stream>>>(dst, bh, E, NB, EPB);
    k_scan1<<<nbs, SCAN_B, 0, stream>>>(bh, eoff, bsum, nscan, buf0, N);
    k_scan2<<<1, SCAN_B, 0, stream>>>(bsum, nbs);
    k_bscatter<<<GB, B, 0, stream>>>(src, dst, eoff, bsum, ebuf, E, NB, EPB);
    k_csr<<<NB, 1024, 0, stream>>>(ebuf, eoff, bsum, rpd, dis, esrcb, N, E, NB);

    // ---- layer 1: Hs1 = fp8((x@W1)*dis); a1 = bf16(relu(dis*sum + b1)) ----
    k_mgemm<128, false, 64, true><<<ngb, B, 0, stream>>>(x, W1, dis,
                                                         (unsigned char*)buf0, N);
    k_agg<0><<<cdiv(N, 4), B, 0, stream>>>((const unsigned char*)buf0, dis, rpd, esrcb,
                                           b1, buf1, N);

    // ---- layer 2: Hs2 = fp8((a1@W2)*dis); a2s = bf16(relu(dis*sum+b2)*dis) ----
    k_mgemm<64, true, 64, true><<<ngb, B, 0, stream>>>(buf1, W2, dis,
                                                       (unsigned char*)buf0, N);
    k_agg<1><<<cdiv(N, 4), B, 0, stream>>>((const unsigned char*)buf0, dis, rpd, esrcb,
                                           b2, buf1, N);

    // ---- layer 3: z = fp8(a2s @ W3) (64 B rows, cols 40-63 = 0); lsm gather ----
    k_mgemm<64, true, 40, false><<<ngb, B, 0, stream>>>(buf1, W3, dis,
                                                        (unsigned char*)buf0, N);
    k_aggz<<<cdiv(N, 4), B, 0, stream>>>((const unsigned char*)buf0, dis, rpd, esrcb,
                                         b3, out, N);
}